// Round 2
// baseline (520.007 us; speedup 1.0000x reference)
//
#include <hip/hip_runtime.h>
#include <hip/hip_bf16.h>
#include <stdint.h>

// Problem constants (match setup_inputs)
#define B_  4
#define S_  2048
#define E_  1024
#define H_  16
#define HD_ 64
#define JD_ 25            // observation_dim + action_dim + 2
#define M_  (B_ * S_)     // 8192 rows for the projections
#define SE_ ((size_t)B_ * S_ * E_)          // 8,388,608
#define EE_ ((size_t)E_ * E_)               // 1,048,576

// workspace layout (ushort units)
#define OFF_HSB  ((size_t)0)
#define OFF_W(i) (SE_ + (size_t)(i) * EE_)
#define OFF_B(i) (SE_ + 4 * EE_ + (size_t)(i) * E_)
#define OFF_Q    (SE_ + 4 * EE_ + 4 * (size_t)E_)
#define OFF_K    (OFF_Q + SE_)
#define OFF_V    (OFF_K + SE_)
#define OFF_O    (OFF_V + SE_)

typedef __attribute__((ext_vector_type(8))) short bf16x8;  // 8 bf16 = 4 VGPRs
typedef __attribute__((ext_vector_type(4))) float f32x4;

// ---- bf16 <-> f32 helpers (bit-level, RNE) ----
__device__ __forceinline__ float b2f(ushort u) {
  union { uint32_t i; float f; } x; x.i = ((uint32_t)u) << 16; return x.f;
}
__device__ __forceinline__ ushort f2b(float f) {
  union { float f; uint32_t i; } x; x.f = f;
  uint32_t i = x.i;
  uint32_t r = (i + 0x7FFFu + ((i >> 16) & 1u)) >> 16;
  return (ushort)r;
}

// Runtime dtype detection: look at even-indexed u16 halves of hidden_states.
// bf16 data: each is a genuine bf16 from N(0,1) -> exponent field in [90,150]
// for all samples. fp32 data: even u16 = low mantissa half -> ~uniform bits,
// only ~24% land in [90,150]. 32 samples, threshold 24: unambiguous.
__device__ bool detect_bf16(const ushort* det) {
  int sane = 0;
#pragma unroll
  for (int i = 0; i < 32; ++i) {
    ushort u = det[2 * i];
    int e = (u >> 7) & 0xFF;
    sane += (e >= 90 && e <= 150) ? 1 : 0;
  }
  return sane >= 24;
}

// async global->LDS, 16B per lane; lds dest must be wave-uniform base (+lane*16 implicit)
__device__ __forceinline__ void async16(const void* g, void* l) {
  __builtin_amdgcn_global_load_lds(
      (const __attribute__((address_space(1))) uint32_t*)g,
      (__attribute__((address_space(3))) uint32_t*)l, 16, 0, 0);
}

// ============================================================================
// Normalize all float inputs to bf16 copies in ws (identity copy if already
// bf16, fp32->bf16 RNE convert otherwise). grid.y picks the tensor.
// ============================================================================
__global__ __launch_bounds__(256)
void convert_kernel(const void* hs, const void* wq, const void* wk,
                    const void* wv, const void* wp,
                    const void* bq, const void* bk, const void* bv, const void* bp,
                    ushort* ws)
{
  __shared__ int dflag;
  if (threadIdx.x == 0) dflag = detect_bf16((const ushort*)hs) ? 1 : 0;
  __syncthreads();
  const bool isb = (dflag != 0);

  const void* src; ushort* dst; size_t n;
  switch (blockIdx.y) {
    case 0: src = hs; dst = ws + OFF_HSB;  n = SE_;        break;
    case 1: src = wq; dst = ws + OFF_W(0); n = EE_;        break;
    case 2: src = wk; dst = ws + OFF_W(1); n = EE_;        break;
    case 3: src = wv; dst = ws + OFF_W(2); n = EE_;        break;
    case 4: src = wp; dst = ws + OFF_W(3); n = EE_;        break;
    case 5: src = bq; dst = ws + OFF_B(0); n = (size_t)E_; break;
    case 6: src = bk; dst = ws + OFF_B(1); n = (size_t)E_; break;
    case 7: src = bv; dst = ws + OFF_B(2); n = (size_t)E_; break;
    default: src = bp; dst = ws + OFF_B(3); n = (size_t)E_; break;
  }
  size_t nv = n >> 2;   // all sizes divisible by 4
  for (size_t i = blockIdx.x * (size_t)blockDim.x + threadIdx.x; i < nv;
       i += (size_t)gridDim.x * blockDim.x) {
    ushort4 o;
    if (isb) {
      o = ((const ushort4*)src)[i];
    } else {
      float4 f = ((const float4*)src)[i];
      o.x = f2b(f.x); o.y = f2b(f.y); o.z = f2b(f.z); o.w = f2b(f.w);
    }
    ((ushort4*)dst)[i] = o;
  }
}

// ============================================================================
// NT GEMM: C[M,N] = A[M,K] * W[N,K]^T + bias   (bf16 in, fp32 acc)
// 128x128 tile, BK=32, 256 threads (4 waves, each 64x64 = 4x4 subtiles 16x16).
// grid.z selects (W,bias,C) triple -> fused QKV in one launch.
// detect_out=0: C is bf16. detect_out=1: C dtype chosen per detect_bf16(det).
// ============================================================================
__global__ __launch_bounds__(256, 2)
void gemm_nt_bias(const ushort* __restrict__ X,
                  const ushort* __restrict__ W0, const ushort* __restrict__ b0, void* __restrict__ C0,
                  const ushort* __restrict__ W1, const ushort* __restrict__ b1, void* __restrict__ C1,
                  const ushort* __restrict__ W2, const ushort* __restrict__ b2, void* __restrict__ C2,
                  int M, int N, int Kd, const ushort* det, int detect_out)
{
  const ushort* W  = (blockIdx.z == 0) ? W0 : (blockIdx.z == 1) ? W1 : W2;
  const ushort* bi = (blockIdx.z == 0) ? b0 : (blockIdx.z == 1) ? b1 : b2;
  void*         C  = (blockIdx.z == 0) ? C0 : (blockIdx.z == 1) ? C1 : C2;

  __shared__ ushort lA[128 * 32];   // [row][k], unpadded (global_load_lds layout)
  __shared__ ushort lB[128 * 32];
  __shared__ int dflag;
  if (threadIdx.x == 0) dflag = (detect_out && !detect_bf16(det)) ? 1 : 0;  // 1 = f32 out
  __syncthreads();
  const bool f32out = (dflag != 0);

  const int tid  = threadIdx.x;
  const int lane = tid & 63;
  const int wv   = tid >> 6;
  const int m0   = blockIdx.x * 128;
  const int n0   = blockIdx.y * 128;
  const int wr   = (wv >> 1) * 64;   // wave row offset in tile
  const int wc   = (wv & 1) * 64;    // wave col offset in tile
  const int ml   = lane & 15;
  const int qd   = lane >> 4;

  f32x4 acc[4][4];
#pragma unroll
  for (int i = 0; i < 4; ++i)
#pragma unroll
    for (int j = 0; j < 4; ++j)
      acc[i][j] = (f32x4){0.f, 0.f, 0.f, 0.f};

  // staging addressing: per round, 256 threads x 16B = 64 rows x 32 k
  const int rowA = tid >> 2;          // 0..63
  const int kvec = (tid & 3) * 8;
  const ushort* gA = X + (size_t)(m0 + rowA) * Kd + kvec;
  const ushort* gW = W + (size_t)(n0 + rowA) * Kd + kvec;
  char* lAb = (char*)lA + (size_t)wv * 1024;  // wave-uniform LDS base
  char* lBb = (char*)lB + (size_t)wv * 1024;

  for (int k0 = 0; k0 < Kd; k0 += 32) {
    async16(gA + k0,                    lAb);
    async16(gA + k0 + (size_t)64 * Kd,  lAb + 4096);
    async16(gW + k0,                    lBb);
    async16(gW + k0 + (size_t)64 * Kd,  lBb + 4096);
    __syncthreads();   // drains vmcnt (global_load_lds) per barrier semantics

    bf16x8 af[4], bfr[4];
#pragma unroll
    for (int i = 0; i < 4; ++i)
      af[i] = *(const bf16x8*)&lA[(wr + i * 16 + ml) * 32 + qd * 8];
#pragma unroll
    for (int j = 0; j < 4; ++j)
      bfr[j] = *(const bf16x8*)&lB[(wc + j * 16 + ml) * 32 + qd * 8];
#pragma unroll
    for (int i = 0; i < 4; ++i)
#pragma unroll
      for (int j = 0; j < 4; ++j)
        acc[i][j] = __builtin_amdgcn_mfma_f32_16x16x32_bf16(af[i], bfr[j], acc[i][j], 0, 0, 0);
    __syncthreads();   // protect LDS before next stage
  }

  // epilogue: C/D layout col=lane&15, row=quad*4+reg
#pragma unroll
  for (int j = 0; j < 4; ++j) {
    int col = n0 + wc + j * 16 + ml;
    float bv = b2f(bi[col]);
#pragma unroll
    for (int i = 0; i < 4; ++i) {
      int row = m0 + wr + i * 16 + qd * 4;
      if (f32out) {
        float* cp = (float*)C + (size_t)row * N + col;
#pragma unroll
        for (int r = 0; r < 4; ++r)
          cp[(size_t)r * N] = acc[i][j][r] + bv;
      } else {
        ushort* cp = (ushort*)C + (size_t)row * N + col;
#pragma unroll
        for (int r = 0; r < 4; ++r)
          cp[(size_t)r * N] = f2b(acc[i][j][r] + bv);
      }
    }
  }
}

// ============================================================================
// Flash attention with periodic causal mask.
// Q/K/V layout: [b][s][h*64+d]  (row stride E_)
// Block = 256 thr (4 waves); block handles (b,h, 64-query tile); wave = 16 q.
// Key tiles of 64; K staged [key][d] LDS, V staged transposed [d][key].
// ============================================================================
__global__ __launch_bounds__(256, 2)
void attn_kernel(const ushort* __restrict__ Qg, const ushort* __restrict__ Kg,
                 const ushort* __restrict__ Vg, ushort* __restrict__ Og)
{
  __shared__ ushort lK[64 * 72];      // [key][d], stride 72 (144B, 16B-aligned)
  __shared__ ushort lV[64 * 72];      // [d][key], stride 72
  __shared__ ushort lP[4][16 * 72];   // per-wave P round-trip [q][key]

  const int qt = blockIdx.x;          // 0..31
  const int bh = blockIdx.y;          // 0..63
  const size_t base = (size_t)(bh >> 4) * S_ * E_ + (size_t)(bh & 15) * HD_;

  const int tid  = threadIdx.x;
  const int lane = tid & 63;
  const int wv   = tid >> 6;
  const int ml   = lane & 15;
  const int qd   = lane >> 4;
  const int q0   = qt * 64 + wv * 16;

  // Q A-frags: A[m=lane&15][k=quad*8+j], two k-halves of hd=64
  bf16x8 qf[2];
  {
    const ushort* qp = Qg + base + (size_t)(q0 + ml) * E_ + qd * 8;
    qf[0] = *(const bf16x8*)qp;
    qf[1] = *(const bf16x8*)(qp + 32);
  }

  f32x4 oacc[4];                       // d-subtiles nb*16, C layout
  float m_i[4], l_i[4];
#pragma unroll
  for (int nb = 0; nb < 4; ++nb) oacc[nb] = (f32x4){0.f, 0.f, 0.f, 0.f};
#pragma unroll
  for (int r = 0; r < 4; ++r) { m_i[r] = -1.0e30f; l_i[r] = 0.f; }

  const int skey = tid >> 3;          // 0..31
  const int sdv  = (tid & 7) * 8;     // 0..56

  for (int kt = 0; kt <= qt; ++kt) {
    __syncthreads();                  // previous-iter LDS reads done
#pragma unroll
    for (int rr = 0; rr < 2; ++rr) {
      int key = rr * 32 + skey;
      const ushort* rp = Kg + base + (size_t)(kt * 64 + key) * E_ + sdv;
      *(bf16x8*)&lK[key * 72 + sdv] = *(const bf16x8*)rp;
      bf16x8 vvec = *(const bf16x8*)(Vg + base + (size_t)(kt * 64 + key) * E_ + sdv);
#pragma unroll
      for (int j = 0; j < 8; ++j)
        lV[(sdv + j) * 72 + key] = (ushort)vvec[j];   // transpose into [d][key]
    }
    __syncthreads();

    // ---- S = Q K^T, scale + mask ----
    float sc[4][4];                   // [kb][reg]
#pragma unroll
    for (int kb = 0; kb < 4; ++kb) {
      f32x4 s = (f32x4){0.f, 0.f, 0.f, 0.f};
      const ushort* krow = &lK[(kb * 16 + ml) * 72 + qd * 8];
      s = __builtin_amdgcn_mfma_f32_16x16x32_bf16(qf[0], *(const bf16x8*)krow,        s, 0, 0, 0);
      s = __builtin_amdgcn_mfma_f32_16x16x32_bf16(qf[1], *(const bf16x8*)(krow + 32), s, 0, 0, 0);
      int key = kt * 64 + kb * 16 + ml;
      bool colok = (key % JD_) != (JD_ - 1);
#pragma unroll
      for (int r = 0; r < 4; ++r) {
        int q = q0 + qd * 4 + r;
        sc[kb][r] = (colok && key <= q) ? s[r] * 0.125f : -1.0e30f;
      }
    }

    // ---- online softmax (rows live in 16-lane groups, per reg) ----
    float alpha[4], pb[4][4];
#pragma unroll
    for (int r = 0; r < 4; ++r) {
      float mx = fmaxf(fmaxf(sc[0][r], sc[1][r]), fmaxf(sc[2][r], sc[3][r]));
      mx = fmaxf(mx, __shfl_xor(mx, 1));
      mx = fmaxf(mx, __shfl_xor(mx, 2));
      mx = fmaxf(mx, __shfl_xor(mx, 4));
      mx = fmaxf(mx, __shfl_xor(mx, 8));
      float mn = fmaxf(m_i[r], mx);
      float al = __expf(m_i[r] - mn);
      m_i[r] = mn; alpha[r] = al;
      float rs = 0.f;
#pragma unroll
      for (int kb = 0; kb < 4; ++kb) {
        float p = __expf(sc[kb][r] - mn);
        pb[kb][r] = p; rs += p;
      }
      rs += __shfl_xor(rs, 1);
      rs += __shfl_xor(rs, 2);
      rs += __shfl_xor(rs, 4);
      rs += __shfl_xor(rs, 8);
      l_i[r] = l_i[r] * al + rs;
    }
#pragma unroll
    for (int nb = 0; nb < 4; ++nb)
#pragma unroll
      for (int r = 0; r < 4; ++r)
        oacc[nb][r] *= alpha[r];

    // ---- P -> LDS (C layout) -> A layout, then O += P V ----
    ushort* pw = lP[wv];
#pragma unroll
    for (int kb = 0; kb < 4; ++kb)
#pragma unroll
      for (int r = 0; r < 4; ++r)
        pw[(qd * 4 + r) * 72 + kb * 16 + ml] = f2b(pb[kb][r]);
    // per-wave region + in-order DS pipeline: no barrier needed
    bf16x8 pa0 = *(const bf16x8*)&pw[ml * 72 + qd * 8];
    bf16x8 pa1 = *(const bf16x8*)&pw[ml * 72 + 32 + qd * 8];
#pragma unroll
    for (int nb = 0; nb < 4; ++nb) {
      const ushort* vrow = &lV[(nb * 16 + ml) * 72 + qd * 8];
      oacc[nb] = __builtin_amdgcn_mfma_f32_16x16x32_bf16(pa0, *(const bf16x8*)vrow,        oacc[nb], 0, 0, 0);
      oacc[nb] = __builtin_amdgcn_mfma_f32_16x16x32_bf16(pa1, *(const bf16x8*)(vrow + 32), oacc[nb], 0, 0, 0);
    }
  }

  // epilogue: O[q][d] = acc/l
#pragma unroll
  for (int nb = 0; nb < 4; ++nb)
#pragma unroll
    for (int r = 0; r < 4; ++r) {
      int q = q0 + qd * 4 + r;
      Og[base + (size_t)q * E_ + nb * 16 + ml] = f2b(oacc[nb][r] / l_i[r]);
    }
}

// ============================================================================
extern "C" void kernel_launch(void* const* d_in, const int* in_sizes, int n_in,
                              void* d_out, int out_size, void* d_ws, size_t ws_size,
                              hipStream_t stream) {
  const void* hs = d_in[0];
  const void* Wq = d_in[1];
  const void* bq = d_in[2];
  const void* Wk = d_in[3];
  const void* bk = d_in[4];
  const void* Wv = d_in[5];
  const void* bv = d_in[6];
  const void* Wp = d_in[7];
  const void* bp = d_in[8];

  ushort* ws = (ushort*)d_ws;
  ushort* hsb = ws + OFF_HSB;
  ushort* Wqb = ws + OFF_W(0);
  ushort* Wkb = ws + OFF_W(1);
  ushort* Wvb = ws + OFF_W(2);
  ushort* Wpb = ws + OFF_W(3);
  ushort* bqb = ws + OFF_B(0);
  ushort* bkb = ws + OFF_B(1);
  ushort* bvb = ws + OFF_B(2);
  ushort* bpb = ws + OFF_B(3);
  ushort* Qw  = ws + OFF_Q;
  ushort* Kw  = ws + OFF_K;
  ushort* Vw  = ws + OFF_V;
  ushort* Ow  = ws + OFF_O;
  const ushort* det = (const ushort*)hs;

  dim3 blk(256, 1, 1);
  // normalize inputs to bf16 ws copies (identity if already bf16)
  hipLaunchKernelGGL(convert_kernel, dim3(512, 9, 1), blk, 0, stream,
                     hs, Wq, Wk, Wv, Wp, bq, bk, bv, bp, ws);
  // fused QKV projections: grid.z picks (W,b,C); bf16 outputs to ws
  hipLaunchKernelGGL(gemm_nt_bias, dim3(M_ / 128, E_ / 128, 3), blk, 0, stream,
                     hsb, Wqb, bqb, (void*)Qw, Wkb, bkb, (void*)Kw,
                     Wvb, bvb, (void*)Vw, M_, E_, E_, det, 0);
  // attention
  hipLaunchKernelGGL(attn_kernel, dim3(S_ / 64, B_ * H_, 1), blk, 0, stream,
                     Qw, Kw, Vw, Ow);
  // output projection: dtype of d_out detected at runtime
  hipLaunchKernelGGL(gemm_nt_bias, dim3(M_ / 128, E_ / 128, 1), blk, 0, stream,
                     Ow, Wpb, bpb, d_out, Wpb, bpb, d_out, Wpb, bpb, d_out,
                     M_, E_, E_, det, 1);
}

// Round 3
// 448.409 us; speedup vs baseline: 1.1597x; 1.1597x over previous
//
#include <hip/hip_runtime.h>
#include <hip/hip_bf16.h>
#include <stdint.h>

// Problem constants (match setup_inputs)
#define B_  4
#define S_  2048
#define E_  1024
#define H_  16
#define HD_ 64
#define JD_ 25            // observation_dim + action_dim + 2
#define M_  (B_ * S_)     // 8192 rows for the projections
#define SE_ ((size_t)B_ * S_ * E_)          // 8,388,608
#define EE_ ((size_t)E_ * E_)               // 1,048,576

// workspace layout (ushort units)
#define OFF_HSB  ((size_t)0)
#define OFF_W(i) (SE_ + (size_t)(i) * EE_)
#define OFF_B(i) (SE_ + 4 * EE_ + (size_t)(i) * E_)
#define OFF_Q    (SE_ + 4 * EE_ + 4 * (size_t)E_)
#define OFF_K    (OFF_Q + SE_)
#define OFF_V    (OFF_K + SE_)   // holds V^T: [feature][b*S+s], row stride M_
#define OFF_O    (OFF_V + SE_)

typedef __attribute__((ext_vector_type(8))) short bf16x8;  // 8 bf16 = 4 VGPRs
typedef __attribute__((ext_vector_type(4))) float f32x4;

__device__ __forceinline__ float b2f(ushort u) {
  union { uint32_t i; float f; } x; x.i = ((uint32_t)u) << 16; return x.f;
}
__device__ __forceinline__ ushort f2b(float f) {
  union { float f; uint32_t i; } x; x.f = f;
  uint32_t i = x.i;
  uint32_t r = (i + 0x7FFFu + ((i >> 16) & 1u)) >> 16;
  return (ushort)r;
}

// Runtime dtype detection on hidden_states (bf16-served vs fp32-served).
__device__ bool detect_bf16(const ushort* det) {
  int sane = 0;
#pragma unroll
  for (int i = 0; i < 32; ++i) {
    ushort u = det[2 * i];
    int e = (u >> 7) & 0xFF;
    sane += (e >= 90 && e <= 150) ? 1 : 0;
  }
  return sane >= 24;
}

__device__ __forceinline__ void async16(const void* g, void* l) {
  __builtin_amdgcn_global_load_lds(
      (const __attribute__((address_space(1))) uint32_t*)g,
      (__attribute__((address_space(3))) uint32_t*)l, 16, 0, 0);
}

// ============================================================================
// Normalize all float inputs to bf16 copies in ws.
// ============================================================================
__global__ __launch_bounds__(256)
void convert_kernel(const void* hs, const void* wq, const void* wk,
                    const void* wv, const void* wp,
                    const void* bq, const void* bk, const void* bv, const void* bp,
                    ushort* ws)
{
  __shared__ int dflag;
  if (threadIdx.x == 0) dflag = detect_bf16((const ushort*)hs) ? 1 : 0;
  __syncthreads();
  const bool isb = (dflag != 0);

  const void* src; ushort* dst; size_t n;
  switch (blockIdx.y) {
    case 0: src = hs; dst = ws + OFF_HSB;  n = SE_;        break;
    case 1: src = wq; dst = ws + OFF_W(0); n = EE_;        break;
    case 2: src = wk; dst = ws + OFF_W(1); n = EE_;        break;
    case 3: src = wv; dst = ws + OFF_W(2); n = EE_;        break;
    case 4: src = wp; dst = ws + OFF_W(3); n = EE_;        break;
    case 5: src = bq; dst = ws + OFF_B(0); n = (size_t)E_; break;
    case 6: src = bk; dst = ws + OFF_B(1); n = (size_t)E_; break;
    case 7: src = bv; dst = ws + OFF_B(2); n = (size_t)E_; break;
    default: src = bp; dst = ws + OFF_B(3); n = (size_t)E_; break;
  }
  size_t nv = n >> 2;
  for (size_t i = blockIdx.x * (size_t)blockDim.x + threadIdx.x; i < nv;
       i += (size_t)gridDim.x * blockDim.x) {
    ushort4 o;
    if (isb) {
      o = ((const ushort4*)src)[i];
    } else {
      float4 f = ((const float4*)src)[i];
      o.x = f2b(f.x); o.y = f2b(f.y); o.z = f2b(f.z); o.w = f2b(f.w);
    }
    ((ushort4*)dst)[i] = o;
  }
}

// ============================================================================
// NT GEMM: C[M,N] = A[M,K] * W[N,K]^T + bias   (bf16 in, fp32 acc)
// 128x128 tile, BK=32, 256 threads. grid.z selects (W,bias,C).
// tz: z-index whose C is stored TRANSPOSED as [N][M] (for V^T), -1 = none.
// detect_out=1: C dtype (f32 vs bf16) chosen at runtime per detect_bf16(det).
// ============================================================================
__global__ __launch_bounds__(256, 2)
void gemm_nt_bias(const ushort* __restrict__ X,
                  const ushort* __restrict__ W0, const ushort* __restrict__ b0, void* __restrict__ C0,
                  const ushort* __restrict__ W1, const ushort* __restrict__ b1, void* __restrict__ C1,
                  const ushort* __restrict__ W2, const ushort* __restrict__ b2, void* __restrict__ C2,
                  int M, int N, int Kd, const ushort* det, int detect_out, int tz)
{
  const ushort* W  = (blockIdx.z == 0) ? W0 : (blockIdx.z == 1) ? W1 : W2;
  const ushort* bi = (blockIdx.z == 0) ? b0 : (blockIdx.z == 1) ? b1 : b2;
  void*         C  = (blockIdx.z == 0) ? C0 : (blockIdx.z == 1) ? C1 : C2;
  const bool tstore = ((int)blockIdx.z == tz);

  __shared__ ushort lA[128 * 32];
  __shared__ ushort lB[128 * 32];
  __shared__ int dflag;
  if (threadIdx.x == 0) dflag = (detect_out && !detect_bf16(det)) ? 1 : 0;
  __syncthreads();
  const bool f32out = (dflag != 0);

  const int tid  = threadIdx.x;
  const int lane = tid & 63;
  const int wv   = tid >> 6;
  const int m0   = blockIdx.x * 128;
  const int n0   = blockIdx.y * 128;
  const int wr   = (wv >> 1) * 64;
  const int wc   = (wv & 1) * 64;
  const int ml   = lane & 15;
  const int qd   = lane >> 4;

  f32x4 acc[4][4];
#pragma unroll
  for (int i = 0; i < 4; ++i)
#pragma unroll
    for (int j = 0; j < 4; ++j)
      acc[i][j] = (f32x4){0.f, 0.f, 0.f, 0.f};

  const int rowA = tid >> 2;
  const int kvec = (tid & 3) * 8;
  const ushort* gA = X + (size_t)(m0 + rowA) * Kd + kvec;
  const ushort* gW = W + (size_t)(n0 + rowA) * Kd + kvec;
  char* lAb = (char*)lA + (size_t)wv * 1024;
  char* lBb = (char*)lB + (size_t)wv * 1024;

  for (int k0 = 0; k0 < Kd; k0 += 32) {
    async16(gA + k0,                    lAb);
    async16(gA + k0 + (size_t)64 * Kd,  lAb + 4096);
    async16(gW + k0,                    lBb);
    async16(gW + k0 + (size_t)64 * Kd,  lBb + 4096);
    __syncthreads();

    bf16x8 af[4], bfr[4];
#pragma unroll
    for (int i = 0; i < 4; ++i)
      af[i] = *(const bf16x8*)&lA[(wr + i * 16 + ml) * 32 + qd * 8];
#pragma unroll
    for (int j = 0; j < 4; ++j)
      bfr[j] = *(const bf16x8*)&lB[(wc + j * 16 + ml) * 32 + qd * 8];
#pragma unroll
    for (int i = 0; i < 4; ++i)
#pragma unroll
      for (int j = 0; j < 4; ++j)
        acc[i][j] = __builtin_amdgcn_mfma_f32_16x16x32_bf16(af[i], bfr[j], acc[i][j], 0, 0, 0);
    __syncthreads();
  }

  // epilogue: C/D layout col=lane&15, row=quad*4+reg
#pragma unroll
  for (int j = 0; j < 4; ++j) {
    int col = n0 + wc + j * 16 + ml;
    float bv = b2f(bi[col]);
#pragma unroll
    for (int i = 0; i < 4; ++i) {
      int row0 = m0 + wr + i * 16 + qd * 4;
      if (tstore) {
        // transposed store: C_t[col][row], 4 consecutive rows -> one 8B store
        ushort4 pk;
        pk.x = f2b(acc[i][j][0] + bv);
        pk.y = f2b(acc[i][j][1] + bv);
        pk.z = f2b(acc[i][j][2] + bv);
        pk.w = f2b(acc[i][j][3] + bv);
        *(ushort4*)((ushort*)C + (size_t)col * M + row0) = pk;
      } else if (f32out) {
        float* cp = (float*)C + (size_t)row0 * N + col;
#pragma unroll
        for (int r = 0; r < 4; ++r)
          cp[(size_t)r * N] = acc[i][j][r] + bv;
      } else {
        ushort* cp = (ushort*)C + (size_t)row0 * N + col;
#pragma unroll
        for (int r = 0; r < 4; ++r)
          cp[(size_t)r * N] = f2b(acc[i][j][r] + bv);
      }
    }
  }
}

// ============================================================================
// Flash attention, periodic causal mask.
// Q/K layout: [b][s][h*64+d] (row stride E_); V^T layout: [h*64+d][b*S+s].
// Block = 256 thr (4 waves) handles (bh, 128-query tile); wave owns 32 q
// (2 m-frags of 16). 64-key tiles; K staged [key][d], V^T staged [d][key],
// both stride 72 (16B-aligned rows), vector ds_write_b128 only.
// Longest blocks launch first (qt reversed) to kill the causal-triangle tail.
// ============================================================================
__global__ __launch_bounds__(256, 2)
void attn_kernel(const ushort* __restrict__ Qg, const ushort* __restrict__ Kg,
                 const ushort* __restrict__ Vt, ushort* __restrict__ Og)
{
  __shared__ ushort lK[64 * 72];      // [key][d]
  __shared__ ushort lV[64 * 72];      // [d][key]
  __shared__ ushort lP[4][16 * 72];   // per-wave P round-trip [q][key]

  const int qt = (int)(gridDim.x - 1 - blockIdx.x);   // long blocks first
  const int bh = blockIdx.y;
  const int b  = bh >> 4, h = bh & 15;
  const size_t base  = (size_t)b * S_ * E_ + (size_t)h * HD_;   // Q,K,O
  const ushort* vtb  = Vt + (size_t)(h * HD_) * M_ + (size_t)b * S_;

  const int tid  = threadIdx.x;
  const int lane = tid & 63;
  const int wv   = tid >> 6;
  const int ml   = lane & 15;
  const int qd   = lane >> 4;
  const int q0w  = qt * 128 + wv * 32;   // wave's 32 queries: m-frags q0w, q0w+16

  // Q A-frags: A[m=lane&15][k=quad*8+j]
  bf16x8 qf[2][2];
#pragma unroll
  for (int mt = 0; mt < 2; ++mt) {
    const ushort* qp = Qg + base + (size_t)(q0w + mt * 16 + ml) * E_ + qd * 8;
    qf[mt][0] = *(const bf16x8*)qp;
    qf[mt][1] = *(const bf16x8*)(qp + 32);
  }

  f32x4 oacc[2][4];
  float m_i[2][4], l_i[2][4];
#pragma unroll
  for (int mt = 0; mt < 2; ++mt) {
#pragma unroll
    for (int nb = 0; nb < 4; ++nb) oacc[mt][nb] = (f32x4){0.f, 0.f, 0.f, 0.f};
#pragma unroll
    for (int r = 0; r < 4; ++r) { m_i[mt][r] = -1.0e30f; l_i[mt][r] = 0.f; }
  }

  const int srow  = tid >> 3;          // 0..31
  const int scol8 = (tid & 7) * 8;     // 0..56
  const int ktmax = 2 * qt + 1;

  for (int kt = 0; kt <= ktmax; ++kt) {
    __syncthreads();                   // previous-iter LDS reads done
#pragma unroll
    for (int rr = 0; rr < 2; ++rr) {
      int sr = rr * 32 + srow;
      // K rows (keys)
      *(bf16x8*)&lK[sr * 72 + scol8] =
          *(const bf16x8*)(Kg + base + (size_t)(kt * 64 + sr) * E_ + scol8);
      // V^T rows (dims), coalesced from global V^T
      *(bf16x8*)&lV[sr * 72 + scol8] =
          *(const bf16x8*)(vtb + (size_t)sr * M_ + kt * 64 + scol8);
    }
    __syncthreads();

    if (kt * 64 <= q0w + 31) {         // wave has any unmasked query
#pragma unroll
      for (int mt = 0; mt < 2; ++mt) {
        // ---- S = Q K^T, scale + mask ----
        float sc[4][4];                // [kb][reg]
#pragma unroll
        for (int kb = 0; kb < 4; ++kb) {
          f32x4 s = (f32x4){0.f, 0.f, 0.f, 0.f};
          const ushort* krow = &lK[(kb * 16 + ml) * 72 + qd * 8];
          s = __builtin_amdgcn_mfma_f32_16x16x32_bf16(qf[mt][0], *(const bf16x8*)krow,        s, 0, 0, 0);
          s = __builtin_amdgcn_mfma_f32_16x16x32_bf16(qf[mt][1], *(const bf16x8*)(krow + 32), s, 0, 0, 0);
          int key = kt * 64 + kb * 16 + ml;
          bool colok = (key % JD_) != (JD_ - 1);
#pragma unroll
          for (int r = 0; r < 4; ++r) {
            int q = q0w + mt * 16 + qd * 4 + r;
            sc[kb][r] = (colok && key <= q) ? s[r] * 0.125f : -1.0e30f;
          }
        }

        // ---- online softmax (row = fixed (qd,r), reduce over 16 ml lanes) ----
        float alpha[4], pb[4][4];
#pragma unroll
        for (int r = 0; r < 4; ++r) {
          float mx = fmaxf(fmaxf(sc[0][r], sc[1][r]), fmaxf(sc[2][r], sc[3][r]));
          mx = fmaxf(mx, __shfl_xor(mx, 1));
          mx = fmaxf(mx, __shfl_xor(mx, 2));
          mx = fmaxf(mx, __shfl_xor(mx, 4));
          mx = fmaxf(mx, __shfl_xor(mx, 8));
          float mn = fmaxf(m_i[mt][r], mx);
          float al = __expf(m_i[mt][r] - mn);
          m_i[mt][r] = mn; alpha[r] = al;
          float rs = 0.f;
#pragma unroll
          for (int kb = 0; kb < 4; ++kb) {
            float p = __expf(sc[kb][r] - mn);
            pb[kb][r] = p; rs += p;
          }
          rs += __shfl_xor(rs, 1);
          rs += __shfl_xor(rs, 2);
          rs += __shfl_xor(rs, 4);
          rs += __shfl_xor(rs, 8);
          l_i[mt][r] = l_i[mt][r] * al + rs;
        }
#pragma unroll
        for (int nb = 0; nb < 4; ++nb)
#pragma unroll
          for (int r = 0; r < 4; ++r)
            oacc[mt][nb][r] *= alpha[r];

        // ---- P -> LDS (C layout) -> A layout, then O += P V ----
        ushort* pw = lP[wv];
#pragma unroll
        for (int kb = 0; kb < 4; ++kb)
#pragma unroll
          for (int r = 0; r < 4; ++r)
            pw[(qd * 4 + r) * 72 + kb * 16 + ml] = f2b(pb[kb][r]);
        // per-wave region + in-order DS pipeline: no barrier needed
        bf16x8 pa0 = *(const bf16x8*)&pw[ml * 72 + qd * 8];
        bf16x8 pa1 = *(const bf16x8*)&pw[ml * 72 + 32 + qd * 8];
#pragma unroll
        for (int nb = 0; nb < 4; ++nb) {
          const ushort* vrow = &lV[(nb * 16 + ml) * 72 + qd * 8];
          oacc[mt][nb] = __builtin_amdgcn_mfma_f32_16x16x32_bf16(pa0, *(const bf16x8*)vrow,        oacc[mt][nb], 0, 0, 0);
          oacc[mt][nb] = __builtin_amdgcn_mfma_f32_16x16x32_bf16(pa1, *(const bf16x8*)(vrow + 32), oacc[mt][nb], 0, 0, 0);
        }
      }
    }
  }

  // epilogue
#pragma unroll
  for (int mt = 0; mt < 2; ++mt)
#pragma unroll
    for (int nb = 0; nb < 4; ++nb)
#pragma unroll
      for (int r = 0; r < 4; ++r) {
        int q = q0w + mt * 16 + qd * 4 + r;
        Og[base + (size_t)q * E_ + nb * 16 + ml] = f2b(oacc[mt][nb][r] / l_i[mt][r]);
      }
}

// ============================================================================
extern "C" void kernel_launch(void* const* d_in, const int* in_sizes, int n_in,
                              void* d_out, int out_size, void* d_ws, size_t ws_size,
                              hipStream_t stream) {
  const void* hs = d_in[0];
  const void* Wq = d_in[1];
  const void* bq = d_in[2];
  const void* Wk = d_in[3];
  const void* bk = d_in[4];
  const void* Wv = d_in[5];
  const void* bv = d_in[6];
  const void* Wp = d_in[7];
  const void* bp = d_in[8];

  ushort* ws = (ushort*)d_ws;
  ushort* hsb = ws + OFF_HSB;
  ushort* Wqb = ws + OFF_W(0);
  ushort* Wkb = ws + OFF_W(1);
  ushort* Wvb = ws + OFF_W(2);
  ushort* Wpb = ws + OFF_W(3);
  ushort* bqb = ws + OFF_B(0);
  ushort* bkb = ws + OFF_B(1);
  ushort* bvb = ws + OFF_B(2);
  ushort* bpb = ws + OFF_B(3);
  ushort* Qw  = ws + OFF_Q;
  ushort* Kw  = ws + OFF_K;
  ushort* Vw  = ws + OFF_V;   // V^T [feature][b*S+s]
  ushort* Ow  = ws + OFF_O;
  const ushort* det = (const ushort*)hs;

  dim3 blk(256, 1, 1);
  hipLaunchKernelGGL(convert_kernel, dim3(512, 9, 1), blk, 0, stream,
                     hs, Wq, Wk, Wv, Wp, bq, bk, bv, bp, ws);
  // fused QKV projections; z==2 (V) stores transposed
  hipLaunchKernelGGL(gemm_nt_bias, dim3(M_ / 128, E_ / 128, 3), blk, 0, stream,
                     hsb, Wqb, bqb, (void*)Qw, Wkb, bkb, (void*)Kw,
                     Wvb, bvb, (void*)Vw, M_, E_, E_, det, 0, 2);
  // attention: 128-query blocks, longest first
  hipLaunchKernelGGL(attn_kernel, dim3(S_ / 128, B_ * H_, 1), blk, 0, stream,
                     Qw, Kw, Vw, Ow);
  // output projection: d_out dtype detected at runtime
  hipLaunchKernelGGL(gemm_nt_bias, dim3(M_ / 128, E_ / 128, 1), blk, 0, stream,
                     Ow, Wpb, bpb, d_out, Wpb, bpb, d_out, Wpb, bpb, d_out,
                     M_, E_, E_, det, 1, -1);
}

// Round 4
// 381.176 us; speedup vs baseline: 1.3642x; 1.1764x over previous
//
#include <hip/hip_runtime.h>
#include <hip/hip_bf16.h>
#include <stdint.h>

// Problem constants (match setup_inputs)
#define B_  4
#define S_  2048
#define E_  1024
#define H_  16
#define HD_ 64
#define JD_ 25            // observation_dim + action_dim + 2
#define M_  (B_ * S_)     // 8192 rows for the projections
#define SE_ ((size_t)B_ * S_ * E_)          // 8,388,608
#define EE_ ((size_t)E_ * E_)               // 1,048,576
#define NQT 16            // 128-query tiles

// workspace layout (ushort units)
#define OFF_HSB  ((size_t)0)
#define OFF_W(i) (SE_ + (size_t)(i) * EE_)
#define OFF_B(i) (SE_ + 4 * EE_ + (size_t)(i) * E_)
#define OFF_Q    (SE_ + 4 * EE_ + 4 * (size_t)E_)
#define OFF_K    (OFF_Q + SE_)
#define OFF_V    (OFF_K + SE_)   // holds V^T: [feature][b*S+s], row stride M_
#define OFF_O    (OFF_V + SE_)

typedef __attribute__((ext_vector_type(8))) short bf16x8;  // 8 bf16 = 4 VGPRs
typedef __attribute__((ext_vector_type(4))) float f32x4;

__device__ __forceinline__ float b2f(ushort u) {
  union { uint32_t i; float f; } x; x.i = ((uint32_t)u) << 16; return x.f;
}
__device__ __forceinline__ ushort f2b(float f) {
  union { float f; uint32_t i; } x; x.f = f;
  uint32_t i = x.i;
  uint32_t r = (i + 0x7FFFu + ((i >> 16) & 1u)) >> 16;
  return (ushort)r;
}

// Runtime dtype detection on hidden_states (bf16-served vs fp32-served).
__device__ bool detect_bf16(const ushort* det) {
  int sane = 0;
#pragma unroll
  for (int i = 0; i < 32; ++i) {
    ushort u = det[2 * i];
    int e = (u >> 7) & 0xFF;
    sane += (e >= 90 && e <= 150) ? 1 : 0;
  }
  return sane >= 24;
}

__device__ __forceinline__ void async16(const void* g, void* l) {
  __builtin_amdgcn_global_load_lds(
      (const __attribute__((address_space(1))) uint32_t*)g,
      (__attribute__((address_space(3))) uint32_t*)l, 16, 0, 0);
}

// ============================================================================
// Normalize all float inputs to bf16 copies in ws.
// ============================================================================
__global__ __launch_bounds__(256)
void convert_kernel(const void* hs, const void* wq, const void* wk,
                    const void* wv, const void* wp,
                    const void* bq, const void* bk, const void* bv, const void* bp,
                    ushort* ws)
{
  __shared__ int dflag;
  if (threadIdx.x == 0) dflag = detect_bf16((const ushort*)hs) ? 1 : 0;
  __syncthreads();
  const bool isb = (dflag != 0);

  const void* src; ushort* dst; size_t n;
  switch (blockIdx.y) {
    case 0: src = hs; dst = ws + OFF_HSB;  n = SE_;        break;
    case 1: src = wq; dst = ws + OFF_W(0); n = EE_;        break;
    case 2: src = wk; dst = ws + OFF_W(1); n = EE_;        break;
    case 3: src = wv; dst = ws + OFF_W(2); n = EE_;        break;
    case 4: src = wp; dst = ws + OFF_W(3); n = EE_;        break;
    case 5: src = bq; dst = ws + OFF_B(0); n = (size_t)E_; break;
    case 6: src = bk; dst = ws + OFF_B(1); n = (size_t)E_; break;
    case 7: src = bv; dst = ws + OFF_B(2); n = (size_t)E_; break;
    default: src = bp; dst = ws + OFF_B(3); n = (size_t)E_; break;
  }
  size_t nv = n >> 2;
  for (size_t i = blockIdx.x * (size_t)blockDim.x + threadIdx.x; i < nv;
       i += (size_t)gridDim.x * blockDim.x) {
    ushort4 o;
    if (isb) {
      o = ((const ushort4*)src)[i];
    } else {
      float4 f = ((const float4*)src)[i];
      o.x = f2b(f.x); o.y = f2b(f.y); o.z = f2b(f.z); o.w = f2b(f.w);
    }
    ((ushort4*)dst)[i] = o;
  }
}

// ============================================================================
// NT GEMM: C[M,N] = (A[M,K] * W[N,K]^T + bias) * scale  (bf16 in, fp32 acc)
// 128x128 tile, BK=32, 256 threads. grid.z selects (W,bias,C).
// tz: z whose C is stored TRANSPOSED [N][M] (V^T). scalez: z scaled by 0.125.
// detect_out=1: C dtype (f32 vs bf16) chosen at runtime per detect_bf16(det).
// ============================================================================
__global__ __launch_bounds__(256, 2)
void gemm_nt_bias(const ushort* __restrict__ X,
                  const ushort* __restrict__ W0, const ushort* __restrict__ b0, void* __restrict__ C0,
                  const ushort* __restrict__ W1, const ushort* __restrict__ b1, void* __restrict__ C1,
                  const ushort* __restrict__ W2, const ushort* __restrict__ b2, void* __restrict__ C2,
                  int M, int N, int Kd, const ushort* det, int detect_out, int tz, int scalez)
{
  const ushort* W  = (blockIdx.z == 0) ? W0 : (blockIdx.z == 1) ? W1 : W2;
  const ushort* bi = (blockIdx.z == 0) ? b0 : (blockIdx.z == 1) ? b1 : b2;
  void*         C  = (blockIdx.z == 0) ? C0 : (blockIdx.z == 1) ? C1 : C2;
  const bool tstore = ((int)blockIdx.z == tz);
  const float scl  = ((int)blockIdx.z == scalez) ? 0.125f : 1.0f;

  __shared__ ushort lA[128 * 32];
  __shared__ ushort lB[128 * 32];
  __shared__ int dflag;
  if (threadIdx.x == 0) dflag = (detect_out && !detect_bf16(det)) ? 1 : 0;
  __syncthreads();
  const bool f32out = (dflag != 0);

  const int tid  = threadIdx.x;
  const int lane = tid & 63;
  const int wv   = tid >> 6;
  const int m0   = blockIdx.x * 128;
  const int n0   = blockIdx.y * 128;
  const int wr   = (wv >> 1) * 64;
  const int wc   = (wv & 1) * 64;
  const int ml   = lane & 15;
  const int qd   = lane >> 4;

  f32x4 acc[4][4];
#pragma unroll
  for (int i = 0; i < 4; ++i)
#pragma unroll
    for (int j = 0; j < 4; ++j)
      acc[i][j] = (f32x4){0.f, 0.f, 0.f, 0.f};

  const int rowA = tid >> 2;
  const int kvec = (tid & 3) * 8;
  const ushort* gA = X + (size_t)(m0 + rowA) * Kd + kvec;
  const ushort* gW = W + (size_t)(n0 + rowA) * Kd + kvec;
  char* lAb = (char*)lA + (size_t)wv * 1024;
  char* lBb = (char*)lB + (size_t)wv * 1024;

  for (int k0 = 0; k0 < Kd; k0 += 32) {
    async16(gA + k0,                    lAb);
    async16(gA + k0 + (size_t)64 * Kd,  lAb + 4096);
    async16(gW + k0,                    lBb);
    async16(gW + k0 + (size_t)64 * Kd,  lBb + 4096);
    __syncthreads();

    bf16x8 af[4], bfr[4];
#pragma unroll
    for (int i = 0; i < 4; ++i)
      af[i] = *(const bf16x8*)&lA[(wr + i * 16 + ml) * 32 + qd * 8];
#pragma unroll
    for (int j = 0; j < 4; ++j)
      bfr[j] = *(const bf16x8*)&lB[(wc + j * 16 + ml) * 32 + qd * 8];
#pragma unroll
    for (int i = 0; i < 4; ++i)
#pragma unroll
      for (int j = 0; j < 4; ++j)
        acc[i][j] = __builtin_amdgcn_mfma_f32_16x16x32_bf16(af[i], bfr[j], acc[i][j], 0, 0, 0);
    __syncthreads();
  }

  // epilogue: C/D layout col=lane&15, row=quad*4+reg
#pragma unroll
  for (int j = 0; j < 4; ++j) {
    int col = n0 + wc + j * 16 + ml;
    float bv = b2f(bi[col]);
#pragma unroll
    for (int i = 0; i < 4; ++i) {
      int row0 = m0 + wr + i * 16 + qd * 4;
      if (tstore) {
        ushort4 pk;
        pk.x = f2b((acc[i][j][0] + bv) * scl);
        pk.y = f2b((acc[i][j][1] + bv) * scl);
        pk.z = f2b((acc[i][j][2] + bv) * scl);
        pk.w = f2b((acc[i][j][3] + bv) * scl);
        *(ushort4*)((ushort*)C + (size_t)col * M + row0) = pk;
      } else if (f32out) {
        float* cp = (float*)C + (size_t)row0 * N + col;
#pragma unroll
        for (int r = 0; r < 4; ++r)
          cp[(size_t)r * N] = (acc[i][j][r] + bv) * scl;
      } else {
        ushort* cp = (ushort*)C + (size_t)row0 * N + col;
#pragma unroll
        for (int r = 0; r < 4; ++r)
          cp[(size_t)r * N] = f2b((acc[i][j][r] + bv) * scl);
      }
    }
  }
}

// ============================================================================
// Flash attention, periodic causal mask. Q is pre-scaled by 0.125.
// Q/K layout: [b][s][h*64+d]; V^T layout: [h*64+d][b*S+s].
// Block = (pair p, bh): handles q-tiles qhi=15-p and qlo=p (128 q each) ->
// uniform 34 compute-iters/block, 512 blocks = exactly 2/CU, zero tail.
// K/V staged via register double-buffer prefetch: next tile's global loads
// issue before current tile's ds_writes (vmcnt never waits on fresh loads).
// ============================================================================
__global__ __launch_bounds__(256, 2)
void attn_kernel(const ushort* __restrict__ Qg, const ushort* __restrict__ Kg,
                 const ushort* __restrict__ Vt, ushort* __restrict__ Og)
{
  __shared__ ushort lK[64 * 72];      // [key][d]
  __shared__ ushort lV[64 * 72];      // [d][key]
  __shared__ ushort lP[4][16 * 72];   // per-wave P round-trip [q][key]

  const int p  = blockIdx.x;          // 0..7
  const int bh = blockIdx.y;
  const int b  = bh >> 4, h = bh & 15;
  const size_t base = (size_t)b * S_ * E_ + (size_t)h * HD_;   // Q,K,O
  const ushort* vtb = Vt + (size_t)(h * HD_) * M_ + (size_t)b * S_;

  const int tid  = threadIdx.x;
  const int lane = tid & 63;
  const int wv   = tid >> 6;
  const int ml   = lane & 15;
  const int qd   = lane >> 4;

  const int qthi = NQT - 1 - p, qtlo = p;
  int q0t[2];
  q0t[0] = qthi * 128 + wv * 32;      // hi tile wave queries
  q0t[1] = qtlo * 128 + wv * 32;      // lo tile wave queries
  const int ktmax = 2 * qthi + 1;

  // Q A-frags for both tiles
  bf16x8 qf[2][2][2];
#pragma unroll
  for (int T = 0; T < 2; ++T)
#pragma unroll
    for (int mt = 0; mt < 2; ++mt) {
      const ushort* qp = Qg + base + (size_t)(q0t[T] + mt * 16 + ml) * E_ + qd * 8;
      qf[T][mt][0] = *(const bf16x8*)qp;
      qf[T][mt][1] = *(const bf16x8*)(qp + 32);
    }

  f32x4 oacc[2][2][4];
  float m_i[2][2][4], l_i[2][2][4];
#pragma unroll
  for (int T = 0; T < 2; ++T)
#pragma unroll
    for (int mt = 0; mt < 2; ++mt) {
#pragma unroll
      for (int nb = 0; nb < 4; ++nb) oacc[T][mt][nb] = (f32x4){0.f, 0.f, 0.f, 0.f};
#pragma unroll
      for (int r = 0; r < 4; ++r) { m_i[T][mt][r] = -1.0e30f; l_i[T][mt][r] = 0.f; }
    }

  const int srow  = tid >> 3;          // 0..31
  const int scol8 = (tid & 7) * 8;     // 0..56
  const ushort* kR0 = Kg + base + (size_t)srow * E_ + scol8;
  const ushort* kR1 = kR0 + (size_t)32 * E_;
  const ushort* vR0 = vtb + (size_t)srow * M_ + scol8;
  const ushort* vR1 = vR0 + (size_t)32 * M_;
  ushort* sK0 = &lK[srow * 72 + scol8];
  ushort* sK1 = &lK[(srow + 32) * 72 + scol8];
  ushort* sV0 = &lV[srow * 72 + scol8];
  ushort* sV1 = &lV[(srow + 32) * 72 + scol8];

#define LDT(K0v,K1v,V0v,V1v,t) { size_t ko = (size_t)(t) * 64 * E_; int vo = (t) * 64; \
    K0v = *(const bf16x8*)(kR0 + ko); K1v = *(const bf16x8*)(kR1 + ko);               \
    V0v = *(const bf16x8*)(vR0 + vo); V1v = *(const bf16x8*)(vR1 + vo); }
#define STT(K0v,K1v,V0v,V1v) { *(bf16x8*)sK0 = K0v; *(bf16x8*)sK1 = K1v;              \
    *(bf16x8*)sV0 = V0v; *(bf16x8*)sV1 = V1v; }

  bf16x8 kA0, kA1, vA0, vA1, kB0, kB1, vB0, vB1;
  LDT(kA0, kA1, vA0, vA1, 0);

  for (int kt = 0; kt <= ktmax; ++kt) {
    const int ktn = (kt < ktmax) ? kt + 1 : kt;
    __syncthreads();                   // previous-iter LDS reads done
    if ((kt & 1) == 0) {
      LDT(kB0, kB1, vB0, vB1, ktn);    // issue next loads FIRST
      STT(kA0, kA1, vA0, vA1);         // write current (already complete)
    } else {
      LDT(kA0, kA1, vA0, vA1, ktn);
      STT(kB0, kB1, vB0, vB1);
    }
    __syncthreads();

#pragma unroll
    for (int T = 0; T < 2; ++T) {
      const int q0w = q0t[T];
      if (kt * 64 <= q0w + 31) {       // wave has any unmasked query
#pragma unroll
        for (int mt = 0; mt < 2; ++mt) {
          // ---- S = Q K^T (Q pre-scaled), mask ----
          float sc[4][4];
#pragma unroll
          for (int kb = 0; kb < 4; ++kb) {
            f32x4 s = (f32x4){0.f, 0.f, 0.f, 0.f};
            const ushort* krow = &lK[(kb * 16 + ml) * 72 + qd * 8];
            s = __builtin_amdgcn_mfma_f32_16x16x32_bf16(qf[T][mt][0], *(const bf16x8*)krow,        s, 0, 0, 0);
            s = __builtin_amdgcn_mfma_f32_16x16x32_bf16(qf[T][mt][1], *(const bf16x8*)(krow + 32), s, 0, 0, 0);
            int key = kt * 64 + kb * 16 + ml;
            bool colok = (key % JD_) != (JD_ - 1);
#pragma unroll
            for (int r = 0; r < 4; ++r) {
              int q = q0w + mt * 16 + qd * 4 + r;
              sc[kb][r] = (colok && key <= q) ? s[r] : -1.0e30f;
            }
          }

          // ---- online softmax ----
          float alpha[4], pb[4][4];
#pragma unroll
          for (int r = 0; r < 4; ++r) {
            float mx = fmaxf(fmaxf(sc[0][r], sc[1][r]), fmaxf(sc[2][r], sc[3][r]));
            mx = fmaxf(mx, __shfl_xor(mx, 1));
            mx = fmaxf(mx, __shfl_xor(mx, 2));
            mx = fmaxf(mx, __shfl_xor(mx, 4));
            mx = fmaxf(mx, __shfl_xor(mx, 8));
            float mn = fmaxf(m_i[T][mt][r], mx);
            float al = __expf(m_i[T][mt][r] - mn);
            m_i[T][mt][r] = mn; alpha[r] = al;
            float rs = 0.f;
#pragma unroll
            for (int kb = 0; kb < 4; ++kb) {
              float pv = __expf(sc[kb][r] - mn);
              pb[kb][r] = pv; rs += pv;
            }
            rs += __shfl_xor(rs, 1);
            rs += __shfl_xor(rs, 2);
            rs += __shfl_xor(rs, 4);
            rs += __shfl_xor(rs, 8);
            l_i[T][mt][r] = l_i[T][mt][r] * al + rs;
          }
#pragma unroll
          for (int nb = 0; nb < 4; ++nb)
#pragma unroll
            for (int r = 0; r < 4; ++r)
              oacc[T][mt][nb][r] *= alpha[r];

          // ---- P -> LDS (C layout) -> A layout, O += P V ----
          ushort* pw = lP[wv];
#pragma unroll
          for (int kb = 0; kb < 4; ++kb)
#pragma unroll
            for (int r = 0; r < 4; ++r)
              pw[(qd * 4 + r) * 72 + kb * 16 + ml] = f2b(pb[kb][r]);
          bf16x8 pa0 = *(const bf16x8*)&pw[ml * 72 + qd * 8];
          bf16x8 pa1 = *(const bf16x8*)&pw[ml * 72 + 32 + qd * 8];
#pragma unroll
          for (int nb = 0; nb < 4; ++nb) {
            const ushort* vrow = &lV[(nb * 16 + ml) * 72 + qd * 8];
            oacc[T][mt][nb] = __builtin_amdgcn_mfma_f32_16x16x32_bf16(pa0, *(const bf16x8*)vrow,        oacc[T][mt][nb], 0, 0, 0);
            oacc[T][mt][nb] = __builtin_amdgcn_mfma_f32_16x16x32_bf16(pa1, *(const bf16x8*)(vrow + 32), oacc[T][mt][nb], 0, 0, 0);
          }
        }
      }
    }
  }
#undef LDT
#undef STT

  // epilogue
#pragma unroll
  for (int T = 0; T < 2; ++T)
#pragma unroll
    for (int mt = 0; mt < 2; ++mt)
#pragma unroll
      for (int nb = 0; nb < 4; ++nb)
#pragma unroll
        for (int r = 0; r < 4; ++r) {
          int q = q0t[T] + mt * 16 + qd * 4 + r;
          Og[base + (size_t)q * E_ + nb * 16 + ml] = f2b(oacc[T][mt][nb][r] / l_i[T][mt][r]);
        }
}

// ============================================================================
extern "C" void kernel_launch(void* const* d_in, const int* in_sizes, int n_in,
                              void* d_out, int out_size, void* d_ws, size_t ws_size,
                              hipStream_t stream) {
  const void* hs = d_in[0];
  const void* Wq = d_in[1];
  const void* bq = d_in[2];
  const void* Wk = d_in[3];
  const void* bk = d_in[4];
  const void* Wv = d_in[5];
  const void* bv = d_in[6];
  const void* Wp = d_in[7];
  const void* bp = d_in[8];

  ushort* ws = (ushort*)d_ws;
  ushort* hsb = ws + OFF_HSB;
  ushort* Wqb = ws + OFF_W(0);
  ushort* Wkb = ws + OFF_W(1);
  ushort* Wvb = ws + OFF_W(2);
  ushort* Wpb = ws + OFF_W(3);
  ushort* bqb = ws + OFF_B(0);
  ushort* bkb = ws + OFF_B(1);
  ushort* bvb = ws + OFF_B(2);
  ushort* bpb = ws + OFF_B(3);
  ushort* Qw  = ws + OFF_Q;
  ushort* Kw  = ws + OFF_K;
  ushort* Vw  = ws + OFF_V;   // V^T [feature][b*S+s]
  ushort* Ow  = ws + OFF_O;
  const ushort* det = (const ushort*)hs;

  dim3 blk(256, 1, 1);
  hipLaunchKernelGGL(convert_kernel, dim3(512, 9, 1), blk, 0, stream,
                     hs, Wq, Wk, Wv, Wp, bq, bk, bv, bp, ws);
  // fused QKV projections; z==2 (V) transposed store; z==0 (Q) pre-scaled 0.125
  hipLaunchKernelGGL(gemm_nt_bias, dim3(M_ / 128, E_ / 128, 3), blk, 0, stream,
                     hsb, Wqb, bqb, (void*)Qw, Wkb, bkb, (void*)Kw,
                     Wvb, bvb, (void*)Vw, M_, E_, E_, det, 0, 2, 0);
  // attention: paired q-tiles, uniform blocks, 2/CU
  hipLaunchKernelGGL(attn_kernel, dim3(NQT / 2, B_ * H_, 1), blk, 0, stream,
                     Qw, Kw, Vw, Ow);
  // output projection: d_out dtype detected at runtime
  hipLaunchKernelGGL(gemm_nt_bias, dim3(M_ / 128, E_ / 128, 1), blk, 0, stream,
                     Ow, Wpb, bpb, d_out, Wpb, bpb, d_out, Wpb, bpb, d_out,
                     M_, E_, E_, det, 1, -1, -1);
}

// Round 5
// 377.160 us; speedup vs baseline: 1.3787x; 1.0106x over previous
//
#include <hip/hip_runtime.h>
#include <hip/hip_bf16.h>
#include <stdint.h>

// Problem constants (match setup_inputs)
#define B_  4
#define S_  2048
#define E_  1024
#define H_  16
#define HD_ 64
#define JD_ 25            // observation_dim + action_dim + 2
#define M_  (B_ * S_)     // 8192 rows for the projections
#define SE_ ((size_t)B_ * S_ * E_)          // 8,388,608
#define EE_ ((size_t)E_ * E_)               // 1,048,576

// Q pre-scale: (1/sqrt(64)) * log2(e) -> scores in log2 domain, exp2 softmax
#define QSCALE 0.18033688011112042f

// workspace layout (ushort units)
#define OFF_HSB  ((size_t)0)
#define OFF_W(i) (SE_ + (size_t)(i) * EE_)
#define OFF_B(i) (SE_ + 4 * EE_ + (size_t)(i) * E_)
#define OFF_Q    (SE_ + 4 * EE_ + 4 * (size_t)E_)
#define OFF_K    (OFF_Q + SE_)
#define OFF_V    (OFF_K + SE_)   // holds V^T: [feature][b*S+s], row stride M_
#define OFF_O    (OFF_V + SE_)

typedef __attribute__((ext_vector_type(8))) short bf16x8;  // 8 bf16 = 4 VGPRs
typedef __attribute__((ext_vector_type(4))) float f32x4;

__device__ __forceinline__ float b2f(ushort u) {
  union { uint32_t i; float f; } x; x.i = ((uint32_t)u) << 16; return x.f;
}
__device__ __forceinline__ ushort f2b(float f) {
  union { float f; uint32_t i; } x; x.f = f;
  uint32_t i = x.i;
  uint32_t r = (i + 0x7FFFu + ((i >> 16) & 1u)) >> 16;
  return (ushort)r;
}

// Runtime dtype detection on hidden_states (bf16-served vs fp32-served).
__device__ bool detect_bf16(const ushort* det) {
  int sane = 0;
#pragma unroll
  for (int i = 0; i < 32; ++i) {
    ushort u = det[2 * i];
    int e = (u >> 7) & 0xFF;
    sane += (e >= 90 && e <= 150) ? 1 : 0;
  }
  return sane >= 24;
}

__device__ __forceinline__ void async16(const void* g, void* l) {
  __builtin_amdgcn_global_load_lds(
      (const __attribute__((address_space(1))) uint32_t*)g,
      (__attribute__((address_space(3))) uint32_t*)l, 16, 0, 0);
}

// ============================================================================
// Normalize all float inputs to bf16 copies in ws.
// ============================================================================
__global__ __launch_bounds__(256)
void convert_kernel(const void* hs, const void* wq, const void* wk,
                    const void* wv, const void* wp,
                    const void* bq, const void* bk, const void* bv, const void* bp,
                    ushort* ws)
{
  __shared__ int dflag;
  if (threadIdx.x == 0) dflag = detect_bf16((const ushort*)hs) ? 1 : 0;
  __syncthreads();
  const bool isb = (dflag != 0);

  const void* src; ushort* dst; size_t n;
  switch (blockIdx.y) {
    case 0: src = hs; dst = ws + OFF_HSB;  n = SE_;        break;
    case 1: src = wq; dst = ws + OFF_W(0); n = EE_;        break;
    case 2: src = wk; dst = ws + OFF_W(1); n = EE_;        break;
    case 3: src = wv; dst = ws + OFF_W(2); n = EE_;        break;
    case 4: src = wp; dst = ws + OFF_W(3); n = EE_;        break;
    case 5: src = bq; dst = ws + OFF_B(0); n = (size_t)E_; break;
    case 6: src = bk; dst = ws + OFF_B(1); n = (size_t)E_; break;
    case 7: src = bv; dst = ws + OFF_B(2); n = (size_t)E_; break;
    default: src = bp; dst = ws + OFF_B(3); n = (size_t)E_; break;
  }
  size_t nv = n >> 2;
  for (size_t i = blockIdx.x * (size_t)blockDim.x + threadIdx.x; i < nv;
       i += (size_t)gridDim.x * blockDim.x) {
    ushort4 o;
    if (isb) {
      o = ((const ushort4*)src)[i];
    } else {
      float4 f = ((const float4*)src)[i];
      o.x = f2b(f.x); o.y = f2b(f.y); o.z = f2b(f.z); o.w = f2b(f.w);
    }
    ((ushort4*)dst)[i] = o;
  }
}

// ============================================================================
// NT GEMM: C[M,N] = (A[M,K] * W[N,K]^T + bias) * scale  (bf16 in, fp32 acc)
// 128x128 tile, BK=32, 256 threads. grid.z selects (W,bias,C).
// tz: z stored TRANSPOSED [N][M] (V^T). scalez: z scaled by QSCALE.
// detect_out=1: C dtype (f32 vs bf16) chosen at runtime per detect_bf16(det).
// ============================================================================
__global__ __launch_bounds__(256, 2)
void gemm_nt_bias(const ushort* __restrict__ X,
                  const ushort* __restrict__ W0, const ushort* __restrict__ b0, void* __restrict__ C0,
                  const ushort* __restrict__ W1, const ushort* __restrict__ b1, void* __restrict__ C1,
                  const ushort* __restrict__ W2, const ushort* __restrict__ b2, void* __restrict__ C2,
                  int M, int N, int Kd, const ushort* det, int detect_out, int tz, int scalez)
{
  const ushort* W  = (blockIdx.z == 0) ? W0 : (blockIdx.z == 1) ? W1 : W2;
  const ushort* bi = (blockIdx.z == 0) ? b0 : (blockIdx.z == 1) ? b1 : b2;
  void*         C  = (blockIdx.z == 0) ? C0 : (blockIdx.z == 1) ? C1 : C2;
  const bool tstore = ((int)blockIdx.z == tz);
  const float scl  = ((int)blockIdx.z == scalez) ? QSCALE : 1.0f;

  __shared__ ushort lA[128 * 32];
  __shared__ ushort lB[128 * 32];
  __shared__ int dflag;
  if (threadIdx.x == 0) dflag = (detect_out && !detect_bf16(det)) ? 1 : 0;
  __syncthreads();
  const bool f32out = (dflag != 0);

  const int tid  = threadIdx.x;
  const int lane = tid & 63;
  const int wv   = tid >> 6;
  const int m0   = blockIdx.x * 128;
  const int n0   = blockIdx.y * 128;
  const int wr   = (wv >> 1) * 64;
  const int wc   = (wv & 1) * 64;
  const int ml   = lane & 15;
  const int qd   = lane >> 4;

  f32x4 acc[4][4];
#pragma unroll
  for (int i = 0; i < 4; ++i)
#pragma unroll
    for (int j = 0; j < 4; ++j)
      acc[i][j] = (f32x4){0.f, 0.f, 0.f, 0.f};

  const int rowA = tid >> 2;
  const int kvec = (tid & 3) * 8;
  const ushort* gA = X + (size_t)(m0 + rowA) * Kd + kvec;
  const ushort* gW = W + (size_t)(n0 + rowA) * Kd + kvec;
  char* lAb = (char*)lA + (size_t)wv * 1024;
  char* lBb = (char*)lB + (size_t)wv * 1024;

  for (int k0 = 0; k0 < Kd; k0 += 32) {
    async16(gA + k0,                    lAb);
    async16(gA + k0 + (size_t)64 * Kd,  lAb + 4096);
    async16(gW + k0,                    lBb);
    async16(gW + k0 + (size_t)64 * Kd,  lBb + 4096);
    __syncthreads();

    bf16x8 af[4], bfr[4];
#pragma unroll
    for (int i = 0; i < 4; ++i)
      af[i] = *(const bf16x8*)&lA[(wr + i * 16 + ml) * 32 + qd * 8];
#pragma unroll
    for (int j = 0; j < 4; ++j)
      bfr[j] = *(const bf16x8*)&lB[(wc + j * 16 + ml) * 32 + qd * 8];
#pragma unroll
    for (int i = 0; i < 4; ++i)
#pragma unroll
      for (int j = 0; j < 4; ++j)
        acc[i][j] = __builtin_amdgcn_mfma_f32_16x16x32_bf16(af[i], bfr[j], acc[i][j], 0, 0, 0);
    __syncthreads();
  }

  // epilogue: C/D layout col=lane&15, row=quad*4+reg
#pragma unroll
  for (int j = 0; j < 4; ++j) {
    int col = n0 + wc + j * 16 + ml;
    float bv = b2f(bi[col]);
#pragma unroll
    for (int i = 0; i < 4; ++i) {
      int row0 = m0 + wr + i * 16 + qd * 4;
      if (tstore) {
        ushort4 pk;
        pk.x = f2b((acc[i][j][0] + bv) * scl);
        pk.y = f2b((acc[i][j][1] + bv) * scl);
        pk.z = f2b((acc[i][j][2] + bv) * scl);
        pk.w = f2b((acc[i][j][3] + bv) * scl);
        *(ushort4*)((ushort*)C + (size_t)col * M + row0) = pk;
      } else if (f32out) {
        float* cp = (float*)C + (size_t)row0 * N + col;
#pragma unroll
        for (int r = 0; r < 4; ++r)
          cp[(size_t)r * N] = (acc[i][j][r] + bv) * scl;
      } else {
        ushort* cp = (ushort*)C + (size_t)row0 * N + col;
#pragma unroll
        for (int r = 0; r < 4; ++r)
          cp[(size_t)r * N] = f2b((acc[i][j][r] + bv) * scl);
      }
    }
  }
}

// ============================================================================
// Flash attention, periodic causal mask. Q pre-scaled by 0.125*log2e ->
// softmax in exp2 domain.
// TRANSPOSED score scheme: S^T = K(A)*Q(B) -> C layout col=q(lane&15),
// row=key(quad*4+reg). Each lane owns one query row: softmax = 15 reg ops +
// 2 shuffles. P^T packed to LDS via ds_write_b64; O^T = V^T(A)*P^T(B).
// Block = (pair p, bh): q-tiles qhi=31-p, qlo=p (64 q each, wave owns 16 q)
// -> uniform 33 compute-units/wave; grid 16x64=1024 = 4 blocks/CU.
// K/V staged via register double-buffer prefetch.
// ============================================================================
__global__ __launch_bounds__(256, 4)
void attn_kernel(const ushort* __restrict__ Qg, const ushort* __restrict__ Kg,
                 const ushort* __restrict__ Vt, ushort* __restrict__ Og)
{
  __shared__ ushort lK[64 * 72];      // [key][d]
  __shared__ ushort lV[64 * 72];      // [d][key]
  __shared__ ushort lP[4][16 * 72];   // per-wave P^T as [q][key]

  const int p  = blockIdx.x;          // 0..15
  const int bh = blockIdx.y;
  const int b  = bh >> 4, h = bh & 15;
  const size_t base = (size_t)b * S_ * E_ + (size_t)h * HD_;   // Q,K,O
  const ushort* vtb = Vt + (size_t)(h * HD_) * M_ + (size_t)b * S_;

  const int tid  = threadIdx.x;
  const int lane = tid & 63;
  const int wv   = tid >> 6;
  const int ml   = lane & 15;
  const int qd   = lane >> 4;

  const int qthi = 31 - p, qtlo = p;
  const int q0t[2] = { qthi * 64 + wv * 16, qtlo * 64 + wv * 16 };
  const int ktmax = qthi;

  // Q B-frags: lane n=ml -> query q0t[T]+ml; k = half*32 + qd*8 + j
  bf16x8 qf[2][2];
#pragma unroll
  for (int T = 0; T < 2; ++T) {
    const ushort* qp = Qg + base + (size_t)(q0t[T] + ml) * E_ + qd * 8;
    qf[T][0] = *(const bf16x8*)qp;
    qf[T][1] = *(const bf16x8*)(qp + 32);
  }

  // O^T accumulators: [T][nb]: col=q=ml, row = d = nb*16 + qd*4 + r
  f32x4 oacc[2][4];
  float m_i[2], l_i[2];
#pragma unroll
  for (int T = 0; T < 2; ++T) {
#pragma unroll
    for (int nb = 0; nb < 4; ++nb) oacc[T][nb] = (f32x4){0.f, 0.f, 0.f, 0.f};
    m_i[T] = -1.0e30f; l_i[T] = 0.f;
  }

  const int srow  = tid >> 3;          // 0..31
  const int scol8 = (tid & 7) * 8;     // 0..56
  const ushort* kR0 = Kg + base + (size_t)srow * E_ + scol8;
  const ushort* kR1 = kR0 + (size_t)32 * E_;
  const ushort* vR0 = vtb + (size_t)srow * M_ + scol8;
  const ushort* vR1 = vR0 + (size_t)32 * M_;
  ushort* sK0 = &lK[srow * 72 + scol8];
  ushort* sK1 = &lK[(srow + 32) * 72 + scol8];
  ushort* sV0 = &lV[srow * 72 + scol8];
  ushort* sV1 = &lV[(srow + 32) * 72 + scol8];

#define LDT(K0v,K1v,V0v,V1v,t) { size_t ko = (size_t)(t) * 64 * E_; int vo = (t) * 64; \
    K0v = *(const bf16x8*)(kR0 + ko); K1v = *(const bf16x8*)(kR1 + ko);               \
    V0v = *(const bf16x8*)(vR0 + vo); V1v = *(const bf16x8*)(vR1 + vo); }
#define STT(K0v,K1v,V0v,V1v) { *(bf16x8*)sK0 = K0v; *(bf16x8*)sK1 = K1v;              \
    *(bf16x8*)sV0 = V0v; *(bf16x8*)sV1 = V1v; }

  bf16x8 kA0, kA1, vA0, vA1, kB0, kB1, vB0, vB1;
  LDT(kA0, kA1, vA0, vA1, 0);

  for (int kt = 0; kt <= ktmax; ++kt) {
    const int ktn = (kt < ktmax) ? kt + 1 : kt;
    __syncthreads();                   // previous-iter LDS reads done
    if ((kt & 1) == 0) {
      LDT(kB0, kB1, vB0, vB1, ktn);    // issue next loads FIRST
      STT(kA0, kA1, vA0, vA1);         // write current (already complete)
    } else {
      LDT(kA0, kA1, vA0, vA1, ktn);
      STT(kB0, kB1, vB0, vB1);
    }
    __syncthreads();

    // wave-uniform bad-column bitmask for this key tile
    uint64_t bad = 0;
    {
      int rem = (kt * 64) % JD_;
      int pp = JD_ - 1 - rem;          // first key_local with key%25==24
      for (; pp < 64; pp += JD_) bad |= 1ull << pp;
    }

#pragma unroll
    for (int T = 0; T < 2; ++T) {
      if (T == 1 && kt > qtlo) continue;   // lo tile done
      const int q    = q0t[T] + ml;        // this lane's query
      const int qrel = q - kt * 64;        // >= 0 when active
      // keep-mask over key_local 0..63
      uint64_t keep = (qrel >= 63) ? ~0ull : ((1ull << (qrel + 1)) - 1ull);
      keep &= ~bad;
      const uint64_t ks   = keep >> (qd * 4);
      const uint32_t k_lo = (uint32_t)ks;
      const uint32_t k_hi = (uint32_t)(ks >> 32);

      // ---- S^T = K Q^T : col=q, row=key ----
      float sc[4][4];                  // [kb][r]: key_local = kb*16+qd*4+r
#pragma unroll
      for (int kb = 0; kb < 4; ++kb) {
        f32x4 s = (f32x4){0.f, 0.f, 0.f, 0.f};
        const ushort* krow = &lK[(kb * 16 + ml) * 72 + qd * 8];
        s = __builtin_amdgcn_mfma_f32_16x16x32_bf16(*(const bf16x8*)krow,        qf[T][0], s, 0, 0, 0);
        s = __builtin_amdgcn_mfma_f32_16x16x32_bf16(*(const bf16x8*)(krow + 32), qf[T][1], s, 0, 0, 0);
        const uint32_t kh = (kb & 1) ? ((kb & 2) ? (k_hi >> 16) : (k_lo >> 16))
                                     : ((kb & 2) ? k_hi : k_lo);
#pragma unroll
        for (int r = 0; r < 4; ++r)
          sc[kb][r] = ((kh >> r) & 1u) ? s[r] : -1.0e30f;
      }

      // ---- softmax: row local in regs, cross-quad via 2 shuffles ----
      float mx = sc[0][0];
#pragma unroll
      for (int kb = 0; kb < 4; ++kb)
#pragma unroll
        for (int r = 0; r < 4; ++r) mx = fmaxf(mx, sc[kb][r]);
      mx = fmaxf(mx, __shfl_xor(mx, 16));
      mx = fmaxf(mx, __shfl_xor(mx, 32));
      const float mn = fmaxf(m_i[T], mx);
      const float al = __builtin_exp2f(m_i[T] - mn);
      m_i[T] = mn;
      float rs = 0.f;
#pragma unroll
      for (int kb = 0; kb < 4; ++kb)
#pragma unroll
        for (int r = 0; r < 4; ++r) {
          float pv = __builtin_exp2f(sc[kb][r] - mn);
          sc[kb][r] = pv; rs += pv;
        }
      rs += __shfl_xor(rs, 16);
      rs += __shfl_xor(rs, 32);
      l_i[T] = l_i[T] * al + rs;
#pragma unroll
      for (int nb = 0; nb < 4; ++nb)
#pragma unroll
        for (int r = 0; r < 4; ++r) oacc[T][nb][r] *= al;

      // ---- P^T -> LDS [q][key] (packed b64), read as B-frag ----
      ushort* pw = lP[wv];
#pragma unroll
      for (int kb = 0; kb < 4; ++kb) {
        ushort4 pk;
        pk.x = f2b(sc[kb][0]); pk.y = f2b(sc[kb][1]);
        pk.z = f2b(sc[kb][2]); pk.w = f2b(sc[kb][3]);
        *(ushort4*)&pw[ml * 72 + kb * 16 + qd * 4] = pk;
      }
      // same-wave in-order DS: no barrier needed
      bf16x8 pa0 = *(const bf16x8*)&pw[ml * 72 + qd * 8];
      bf16x8 pa1 = *(const bf16x8*)&pw[ml * 72 + 32 + qd * 8];

      // ---- O^T += V^T(A) * P^T(B) ----
#pragma unroll
      for (int nb = 0; nb < 4; ++nb) {
        const ushort* vrow = &lV[(nb * 16 + ml) * 72 + qd * 8];
        oacc[T][nb] = __builtin_amdgcn_mfma_f32_16x16x32_bf16(*(const bf16x8*)vrow,        pa0, oacc[T][nb], 0, 0, 0);
        oacc[T][nb] = __builtin_amdgcn_mfma_f32_16x16x32_bf16(*(const bf16x8*)(vrow + 32), pa1, oacc[T][nb], 0, 0, 0);
      }
    }
  }
#undef LDT
#undef STT

  // epilogue: lane owns query q0t[T]+ml; d = nb*16 + qd*4 + r (4 contiguous)
#pragma unroll
  for (int T = 0; T < 2; ++T) {
    const float inv = 1.0f / l_i[T];
    const int q = q0t[T] + ml;
#pragma unroll
    for (int nb = 0; nb < 4; ++nb) {
      ushort4 o;
      o.x = f2b(oacc[T][nb][0] * inv);
      o.y = f2b(oacc[T][nb][1] * inv);
      o.z = f2b(oacc[T][nb][2] * inv);
      o.w = f2b(oacc[T][nb][3] * inv);
      *(ushort4*)&Og[base + (size_t)q * E_ + nb * 16 + qd * 4] = o;
    }
  }
}

// ============================================================================
extern "C" void kernel_launch(void* const* d_in, const int* in_sizes, int n_in,
                              void* d_out, int out_size, void* d_ws, size_t ws_size,
                              hipStream_t stream) {
  const void* hs = d_in[0];
  const void* Wq = d_in[1];
  const void* bq = d_in[2];
  const void* Wk = d_in[3];
  const void* bk = d_in[4];
  const void* Wv = d_in[5];
  const void* bv = d_in[6];
  const void* Wp = d_in[7];
  const void* bp = d_in[8];

  ushort* ws = (ushort*)d_ws;
  ushort* hsb = ws + OFF_HSB;
  ushort* Wqb = ws + OFF_W(0);
  ushort* Wkb = ws + OFF_W(1);
  ushort* Wvb = ws + OFF_W(2);
  ushort* Wpb = ws + OFF_W(3);
  ushort* bqb = ws + OFF_B(0);
  ushort* bkb = ws + OFF_B(1);
  ushort* bvb = ws + OFF_B(2);
  ushort* bpb = ws + OFF_B(3);
  ushort* Qw  = ws + OFF_Q;
  ushort* Kw  = ws + OFF_K;
  ushort* Vw  = ws + OFF_V;   // V^T [feature][b*S+s]
  ushort* Ow  = ws + OFF_O;
  const ushort* det = (const ushort*)hs;

  dim3 blk(256, 1, 1);
  hipLaunchKernelGGL(convert_kernel, dim3(512, 9, 1), blk, 0, stream,
                     hs, Wq, Wk, Wv, Wp, bq, bk, bv, bp, ws);
  // fused QKV projections; z==2 (V) transposed store; z==0 (Q) scaled QSCALE
  hipLaunchKernelGGL(gemm_nt_bias, dim3(M_ / 128, E_ / 128, 3), blk, 0, stream,
                     hsb, Wqb, bqb, (void*)Qw, Wkb, bkb, (void*)Kw,
                     Wvb, bvb, (void*)Vw, M_, E_, E_, det, 0, 2, 0);
  // attention: paired 64-query tiles, 1024 blocks = 4/CU
  hipLaunchKernelGGL(attn_kernel, dim3(16, B_ * H_, 1), blk, 0, stream,
                     Qw, Kw, Vw, Ow);
  // output projection: d_out dtype detected at runtime
  hipLaunchKernelGGL(gemm_nt_bias, dim3(M_ / 128, E_ / 128, 1), blk, 0, stream,
                     Ow, Wpb, bpb, d_out, Wpb, bpb, d_out, Wpb, bpb, d_out,
                     M_, E_, E_, det, 1, -1, -1);
}

// Round 6
// 311.676 us; speedup vs baseline: 1.6684x; 1.2101x over previous
//
#include <hip/hip_runtime.h>
#include <hip/hip_bf16.h>
#include <stdint.h>

// Problem constants (match setup_inputs)
#define B_  4
#define S_  2048
#define E_  1024
#define H_  16
#define HD_ 64
#define JD_ 25            // observation_dim + action_dim + 2
#define M_  (B_ * S_)     // 8192 rows for the projections
#define SE_ ((size_t)B_ * S_ * E_)          // 8,388,608
#define EE_ ((size_t)E_ * E_)               // 1,048,576

// Q pre-scale: (1/sqrt(64)) * log2(e) -> scores in log2 domain, exp2 softmax
#define QSCALE 0.18033688011112042f

// workspace layout (ushort units)
#define OFF_HSB  ((size_t)0)
#define OFF_W(i) (SE_ + (size_t)(i) * EE_)
#define OFF_B(i) (SE_ + 4 * EE_ + (size_t)(i) * E_)
#define OFF_Q    (SE_ + 4 * EE_ + 4 * (size_t)E_)
#define OFF_K    (OFF_Q + SE_)
#define OFF_V    (OFF_K + SE_)   // holds V^T: [feature][b*S+s], row stride M_
#define OFF_O    (OFF_V + SE_)

typedef __attribute__((ext_vector_type(8))) short bf16x8;  // 8 bf16 = 4 VGPRs
typedef __attribute__((ext_vector_type(4))) float f32x4;

__device__ __forceinline__ float b2f(ushort u) {
  union { uint32_t i; float f; } x; x.i = ((uint32_t)u) << 16; return x.f;
}
__device__ __forceinline__ ushort f2b(float f) {
  union { float f; uint32_t i; } x; x.f = f;
  uint32_t i = x.i;
  uint32_t r = (i + 0x7FFFu + ((i >> 16) & 1u)) >> 16;
  return (ushort)r;
}

// Runtime dtype detection on hidden_states (bf16-served vs fp32-served).
__device__ bool detect_bf16(const ushort* det) {
  int sane = 0;
#pragma unroll
  for (int i = 0; i < 32; ++i) {
    ushort u = det[2 * i];
    int e = (u >> 7) & 0xFF;
    sane += (e >= 90 && e <= 150) ? 1 : 0;
  }
  return sane >= 24;
}

__device__ __forceinline__ void async16(const void* g, void* l) {
  __builtin_amdgcn_global_load_lds(
      (const __attribute__((address_space(1))) uint32_t*)g,
      (__attribute__((address_space(3))) uint32_t*)l, 16, 0, 0);
}

// ============================================================================
// Normalize all float inputs to bf16 copies in ws.
// ============================================================================
__global__ __launch_bounds__(256)
void convert_kernel(const void* hs, const void* wq, const void* wk,
                    const void* wv, const void* wp,
                    const void* bq, const void* bk, const void* bv, const void* bp,
                    ushort* ws)
{
  __shared__ int dflag;
  if (threadIdx.x == 0) dflag = detect_bf16((const ushort*)hs) ? 1 : 0;
  __syncthreads();
  const bool isb = (dflag != 0);

  const void* src; ushort* dst; size_t n;
  switch (blockIdx.y) {
    case 0: src = hs; dst = ws + OFF_HSB;  n = SE_;        break;
    case 1: src = wq; dst = ws + OFF_W(0); n = EE_;        break;
    case 2: src = wk; dst = ws + OFF_W(1); n = EE_;        break;
    case 3: src = wv; dst = ws + OFF_W(2); n = EE_;        break;
    case 4: src = wp; dst = ws + OFF_W(3); n = EE_;        break;
    case 5: src = bq; dst = ws + OFF_B(0); n = (size_t)E_; break;
    case 6: src = bk; dst = ws + OFF_B(1); n = (size_t)E_; break;
    case 7: src = bv; dst = ws + OFF_B(2); n = (size_t)E_; break;
    default: src = bp; dst = ws + OFF_B(3); n = (size_t)E_; break;
  }
  size_t nv = n >> 2;
  for (size_t i = blockIdx.x * (size_t)blockDim.x + threadIdx.x; i < nv;
       i += (size_t)gridDim.x * blockDim.x) {
    ushort4 o;
    if (isb) {
      o = ((const ushort4*)src)[i];
    } else {
      float4 f = ((const float4*)src)[i];
      o.x = f2b(f.x); o.y = f2b(f.y); o.z = f2b(f.z); o.w = f2b(f.w);
    }
    ((ushort4*)dst)[i] = o;
  }
}

// ============================================================================
// NT GEMM: C[M,N] = (A[M,K] * W[N,K]^T + bias) * scale  (bf16 in, fp32 acc)
// 128x128 tile, BK=32, 256 threads. grid.z selects (W,bias,C).
// tz: z stored TRANSPOSED [N][M] (V^T). scalez: z scaled by QSCALE.
// detect_out=1: C dtype (f32 vs bf16) chosen at runtime per detect_bf16(det).
// ============================================================================
__global__ __launch_bounds__(256, 2)
void gemm_nt_bias(const ushort* __restrict__ X,
                  const ushort* __restrict__ W0, const ushort* __restrict__ b0, void* __restrict__ C0,
                  const ushort* __restrict__ W1, const ushort* __restrict__ b1, void* __restrict__ C1,
                  const ushort* __restrict__ W2, const ushort* __restrict__ b2, void* __restrict__ C2,
                  int M, int N, int Kd, const ushort* det, int detect_out, int tz, int scalez)
{
  const ushort* W  = (blockIdx.z == 0) ? W0 : (blockIdx.z == 1) ? W1 : W2;
  const ushort* bi = (blockIdx.z == 0) ? b0 : (blockIdx.z == 1) ? b1 : b2;
  void*         C  = (blockIdx.z == 0) ? C0 : (blockIdx.z == 1) ? C1 : C2;
  const bool tstore = ((int)blockIdx.z == tz);
  const float scl  = ((int)blockIdx.z == scalez) ? QSCALE : 1.0f;

  __shared__ ushort lA[128 * 32];
  __shared__ ushort lB[128 * 32];
  __shared__ int dflag;
  if (threadIdx.x == 0) dflag = (detect_out && !detect_bf16(det)) ? 1 : 0;
  __syncthreads();
  const bool f32out = (dflag != 0);

  const int tid  = threadIdx.x;
  const int lane = tid & 63;
  const int wv   = tid >> 6;
  const int m0   = blockIdx.x * 128;
  const int n0   = blockIdx.y * 128;
  const int wr   = (wv >> 1) * 64;
  const int wc   = (wv & 1) * 64;
  const int ml   = lane & 15;
  const int qd   = lane >> 4;

  f32x4 acc[4][4];
#pragma unroll
  for (int i = 0; i < 4; ++i)
#pragma unroll
    for (int j = 0; j < 4; ++j)
      acc[i][j] = (f32x4){0.f, 0.f, 0.f, 0.f};

  const int rowA = tid >> 2;
  const int kvec = (tid & 3) * 8;
  const ushort* gA = X + (size_t)(m0 + rowA) * Kd + kvec;
  const ushort* gW = W + (size_t)(n0 + rowA) * Kd + kvec;
  char* lAb = (char*)lA + (size_t)wv * 1024;
  char* lBb = (char*)lB + (size_t)wv * 1024;

  for (int k0 = 0; k0 < Kd; k0 += 32) {
    async16(gA + k0,                    lAb);
    async16(gA + k0 + (size_t)64 * Kd,  lAb + 4096);
    async16(gW + k0,                    lBb);
    async16(gW + k0 + (size_t)64 * Kd,  lBb + 4096);
    __syncthreads();

    bf16x8 af[4], bfr[4];
#pragma unroll
    for (int i = 0; i < 4; ++i)
      af[i] = *(const bf16x8*)&lA[(wr + i * 16 + ml) * 32 + qd * 8];
#pragma unroll
    for (int j = 0; j < 4; ++j)
      bfr[j] = *(const bf16x8*)&lB[(wc + j * 16 + ml) * 32 + qd * 8];
#pragma unroll
    for (int i = 0; i < 4; ++i)
#pragma unroll
      for (int j = 0; j < 4; ++j)
        acc[i][j] = __builtin_amdgcn_mfma_f32_16x16x32_bf16(af[i], bfr[j], acc[i][j], 0, 0, 0);
    __syncthreads();
  }

  // epilogue: C/D layout col=lane&15, row=quad*4+reg
#pragma unroll
  for (int j = 0; j < 4; ++j) {
    int col = n0 + wc + j * 16 + ml;
    float bv = b2f(bi[col]);
#pragma unroll
    for (int i = 0; i < 4; ++i) {
      int row0 = m0 + wr + i * 16 + qd * 4;
      if (tstore) {
        ushort4 pk;
        pk.x = f2b((acc[i][j][0] + bv) * scl);
        pk.y = f2b((acc[i][j][1] + bv) * scl);
        pk.z = f2b((acc[i][j][2] + bv) * scl);
        pk.w = f2b((acc[i][j][3] + bv) * scl);
        *(ushort4*)((ushort*)C + (size_t)col * M + row0) = pk;
      } else if (f32out) {
        float* cp = (float*)C + (size_t)row0 * N + col;
#pragma unroll
        for (int r = 0; r < 4; ++r)
          cp[(size_t)r * N] = (acc[i][j][r] + bv) * scl;
      } else {
        ushort* cp = (ushort*)C + (size_t)row0 * N + col;
#pragma unroll
        for (int r = 0; r < 4; ++r)
          cp[(size_t)r * N] = f2b((acc[i][j][r] + bv) * scl);
      }
    }
  }
}

// ============================================================================
// Flash attention, periodic causal mask. Q pre-scaled by 0.125*log2e ->
// softmax in exp2 domain. Transposed scores: S^T = K(A)*Q(B), per-lane
// softmax rows, P^T via swizzled LDS, O^T = V^T(A)*P^T(B).
// K/V staged by global_load_lds(16B) into UNPADDED XOR-swizzled LDS tiles
// (chunk c of row r stored at c^(r&7)); double-buffered, one barrier/iter,
// prefetch issued after barrier -> loads in flight across whole compute.
// Grid: 1024 1D blocks, XCD-swizzled so 16 blocks sharing one bh's K/V run
// on one XCD (L2 reuse). 40KB LDS = exactly 4 blocks/CU.
// ============================================================================
__global__ __launch_bounds__(256, 2)
void attn_kernel(const ushort* __restrict__ Qg, const ushort* __restrict__ Kg,
                 const ushort* __restrict__ Vt, ushort* __restrict__ Og)
{
  __shared__ ushort lK[2][64 * 64];   // [key][d] swizzled, 8KB each
  __shared__ ushort lV[2][64 * 64];   // [d][key] swizzled
  __shared__ ushort lP[4][16 * 64];   // per-wave P^T [q][key] swizzled

  // XCD-aware decode: xcd = lin&7; all 16 p-blocks of a bh on one XCD
  const int lin = blockIdx.x;
  const int bh  = (lin & 7) * 8 + (lin >> 7);       // 0..63
  const int p   = (lin >> 3) & 15;                  // 0..15
  const int b = bh >> 4, h = bh & 15;
  const size_t base = (size_t)b * S_ * E_ + (size_t)h * HD_;   // Q,K,O
  const ushort* vtb = Vt + (size_t)(h * HD_) * M_ + (size_t)b * S_;

  const int tid  = threadIdx.x;
  const int lane = tid & 63;
  const int wv   = tid >> 6;
  const int ml   = lane & 15;
  const int qd   = lane >> 4;
  const int sx   = ml & 7;            // XOR swizzle key for this lane's reads

  const int qthi = 31 - p, qtlo = p;
  const int q0t[2] = { qthi * 64 + wv * 16, qtlo * 64 + wv * 16 };
  const int ktmax = qthi;

  // Q B-frags: lane n=ml -> query q0t[T]+ml; k = half*32 + qd*8 + j
  bf16x8 qf[2][2];
#pragma unroll
  for (int T = 0; T < 2; ++T) {
    const ushort* qp = Qg + base + (size_t)(q0t[T] + ml) * E_ + qd * 8;
    qf[T][0] = *(const bf16x8*)qp;
    qf[T][1] = *(const bf16x8*)(qp + 32);
  }

  f32x4 oacc[2][4];
  float m_i[2], l_i[2];
#pragma unroll
  for (int T = 0; T < 2; ++T) {
#pragma unroll
    for (int nb = 0; nb < 4; ++nb) oacc[T][nb] = (f32x4){0.f, 0.f, 0.f, 0.f};
    m_i[T] = -1.0e30f; l_i[T] = 0.f;
  }

  // staging: 8 rounds of 1KB (4 waves x 2); lane covers 16B chunk g.
  // stored chunk s holds data chunk s^(row&7) -> lane loads permuted global.
  const int g0 = (wv * 2) * 64 + lane;       // round 0 chunk id
  const int g1 = g0 + 64;                    // round 1
  const int r0 = g0 >> 3, c0 = ((g0 & 7) ^ (r0 & 7)) * 8;
  const int r1 = g1 >> 3, c1 = ((g1 & 7) ^ (r1 & 7)) * 8;
  const ushort* kS0 = Kg + base + (size_t)r0 * E_ + c0;
  const ushort* kS1 = Kg + base + (size_t)r1 * E_ + c1;
  const ushort* vS0 = vtb + (size_t)r0 * M_ + c0;
  const ushort* vS1 = vtb + (size_t)r1 * M_ + c1;
  const int d0 = (wv * 2) * 512, d1 = d0 + 512;   // ushort offsets, wave-uniform

#define ISSUE(bi_, t_) { size_t ko = (size_t)(t_) * 64 * E_; int vo = (t_) * 64; \
    async16(kS0 + ko, &lK[bi_][d0]); async16(kS1 + ko, &lK[bi_][d1]);            \
    async16(vS0 + vo, &lV[bi_][d0]); async16(vS1 + vo, &lV[bi_][d1]); }

  ISSUE(0, 0);

  for (int kt = 0; kt <= ktmax; ++kt) {
    __syncthreads();                   // drains tile-kt loads; prev compute done
    if (kt < ktmax) ISSUE((kt + 1) & 1, kt + 1);
    const ushort* bK = lK[kt & 1];
    const ushort* bV = lV[kt & 1];

    // wave-uniform bad-column bitmask for this key tile
    uint64_t bad = 0;
    {
      int rem = (kt * 64) % JD_;
      int pp = JD_ - 1 - rem;
      for (; pp < 64; pp += JD_) bad |= 1ull << pp;
    }

#pragma unroll
    for (int T = 0; T < 2; ++T) {
      if (T == 1 && kt > qtlo) continue;   // lo tile done
      const int q    = q0t[T] + ml;
      const int qrel = q - kt * 64;
      uint64_t keep = (qrel >= 63) ? ~0ull : ((1ull << (qrel + 1)) - 1ull);
      keep &= ~bad;
      const uint64_t ks   = keep >> (qd * 4);
      const uint32_t k_lo = (uint32_t)ks;
      const uint32_t k_hi = (uint32_t)(ks >> 32);

      // ---- S^T = K Q^T : col=q, row=key ----
      float sc[4][4];                  // [kb][r]: key_local = kb*16+qd*4+r
#pragma unroll
      for (int kb = 0; kb < 4; ++kb) {
        f32x4 s = (f32x4){0.f, 0.f, 0.f, 0.f};
        const ushort* krow = &bK[(kb * 16 + ml) * 64];
        s = __builtin_amdgcn_mfma_f32_16x16x32_bf16(*(const bf16x8*)&krow[(qd ^ sx) * 8],       qf[T][0], s, 0, 0, 0);
        s = __builtin_amdgcn_mfma_f32_16x16x32_bf16(*(const bf16x8*)&krow[((qd + 4) ^ sx) * 8], qf[T][1], s, 0, 0, 0);
        const uint32_t kh = (kb & 1) ? ((kb & 2) ? (k_hi >> 16) : (k_lo >> 16))
                                     : ((kb & 2) ? k_hi : k_lo);
#pragma unroll
        for (int r = 0; r < 4; ++r)
          sc[kb][r] = ((kh >> r) & 1u) ? s[r] : -1.0e30f;
      }

      // ---- softmax: per-lane row, 2 shuffles cross-quad ----
      float mx = sc[0][0];
#pragma unroll
      for (int kb = 0; kb < 4; ++kb)
#pragma unroll
        for (int r = 0; r < 4; ++r) mx = fmaxf(mx, sc[kb][r]);
      mx = fmaxf(mx, __shfl_xor(mx, 16));
      mx = fmaxf(mx, __shfl_xor(mx, 32));
      const float mn = fmaxf(m_i[T], mx);
      const float al = __builtin_exp2f(m_i[T] - mn);
      m_i[T] = mn;
      float rs = 0.f;
#pragma unroll
      for (int kb = 0; kb < 4; ++kb)
#pragma unroll
        for (int r = 0; r < 4; ++r) {
          float pv = __builtin_exp2f(sc[kb][r] - mn);
          sc[kb][r] = pv; rs += pv;
        }
      rs += __shfl_xor(rs, 16);
      rs += __shfl_xor(rs, 32);
      l_i[T] = l_i[T] * al + rs;
#pragma unroll
      for (int nb = 0; nb < 4; ++nb)
#pragma unroll
        for (int r = 0; r < 4; ++r) oacc[T][nb][r] *= al;

      // ---- P^T -> swizzled LDS [q][key] (b64 writes), read as B-frag ----
      ushort* pw = lP[wv];
      const int sub = (qd & 1) * 4;
#pragma unroll
      for (int kb = 0; kb < 4; ++kb) {
        ushort4 pk;
        pk.x = f2b(sc[kb][0]); pk.y = f2b(sc[kb][1]);
        pk.z = f2b(sc[kb][2]); pk.w = f2b(sc[kb][3]);
        const int s_ = (kb * 2 + (qd >> 1)) ^ sx;
        *(ushort4*)&pw[ml * 64 + s_ * 8 + sub] = pk;
      }
      // same-wave in-order DS: no barrier needed
      bf16x8 pa0 = *(const bf16x8*)&pw[ml * 64 + ((qd ^ sx)) * 8];
      bf16x8 pa1 = *(const bf16x8*)&pw[ml * 64 + (((qd + 4) ^ sx)) * 8];

      // ---- O^T += V^T(A) * P^T(B) ----
#pragma unroll
      for (int nb = 0; nb < 4; ++nb) {
        const ushort* vrow = &bV[(nb * 16 + ml) * 64];
        oacc[T][nb] = __builtin_amdgcn_mfma_f32_16x16x32_bf16(*(const bf16x8*)&vrow[(qd ^ sx) * 8],       pa0, oacc[T][nb], 0, 0, 0);
        oacc[T][nb] = __builtin_amdgcn_mfma_f32_16x16x32_bf16(*(const bf16x8*)&vrow[((qd + 4) ^ sx) * 8], pa1, oacc[T][nb], 0, 0, 0);
      }
    }
  }
#undef ISSUE

  // epilogue: lane owns query q0t[T]+ml; d = nb*16 + qd*4 + r (4 contiguous)
#pragma unroll
  for (int T = 0; T < 2; ++T) {
    const float inv = 1.0f / l_i[T];
    const int q = q0t[T] + ml;
#pragma unroll
    for (int nb = 0; nb < 4; ++nb) {
      ushort4 o;
      o.x = f2b(oacc[T][nb][0] * inv);
      o.y = f2b(oacc[T][nb][1] * inv);
      o.z = f2b(oacc[T][nb][2] * inv);
      o.w = f2b(oacc[T][nb][3] * inv);
      *(ushort4*)&Og[base + (size_t)q * E_ + nb * 16 + qd * 4] = o;
    }
  }
}

// ============================================================================
extern "C" void kernel_launch(void* const* d_in, const int* in_sizes, int n_in,
                              void* d_out, int out_size, void* d_ws, size_t ws_size,
                              hipStream_t stream) {
  const void* hs = d_in[0];
  const void* Wq = d_in[1];
  const void* bq = d_in[2];
  const void* Wk = d_in[3];
  const void* bk = d_in[4];
  const void* Wv = d_in[5];
  const void* bv = d_in[6];
  const void* Wp = d_in[7];
  const void* bp = d_in[8];

  ushort* ws = (ushort*)d_ws;
  ushort* hsb = ws + OFF_HSB;
  ushort* Wqb = ws + OFF_W(0);
  ushort* Wkb = ws + OFF_W(1);
  ushort* Wvb = ws + OFF_W(2);
  ushort* Wpb = ws + OFF_W(3);
  ushort* bqb = ws + OFF_B(0);
  ushort* bkb = ws + OFF_B(1);
  ushort* bvb = ws + OFF_B(2);
  ushort* bpb = ws + OFF_B(3);
  ushort* Qw  = ws + OFF_Q;
  ushort* Kw  = ws + OFF_K;
  ushort* Vw  = ws + OFF_V;   // V^T [feature][b*S+s]
  ushort* Ow  = ws + OFF_O;
  const ushort* det = (const ushort*)hs;

  dim3 blk(256, 1, 1);
  hipLaunchKernelGGL(convert_kernel, dim3(512, 9, 1), blk, 0, stream,
                     hs, Wq, Wk, Wv, Wp, bq, bk, bv, bp, ws);
  // fused QKV projections; z==2 (V) transposed store; z==0 (Q) scaled QSCALE
  hipLaunchKernelGGL(gemm_nt_bias, dim3(M_ / 128, E_ / 128, 3), blk, 0, stream,
                     hsb, Wqb, bqb, (void*)Qw, Wkb, bkb, (void*)Kw,
                     Wvb, bvb, (void*)Vw, M_, E_, E_, det, 0, 2, 0);
  // attention: 1024 1D blocks, XCD-swizzled, 4 blocks/CU
  hipLaunchKernelGGL(attn_kernel, dim3(1024, 1, 1), blk, 0, stream,
                     Qw, Kw, Vw, Ow);
  // output projection: d_out dtype detected at runtime
  hipLaunchKernelGGL(gemm_nt_bias, dim3(M_ / 128, E_ / 128, 1), blk, 0, stream,
                     Ow, Wpb, bpb, d_out, Wpb, bpb, d_out, Wpb, bpb, d_out,
                     M_, E_, E_, det, 1, -1, -1);
}